// Round 11
// baseline (989.953 us; speedup 1.0000x reference)
//
#include <hip/hip_runtime.h>
#include <math.h>

#define NN   30000
#define EE   480000
#define ETOT 510000   // EE + NN self loops
#define BB   48
#define HHH  4
#define DDD  64
#define CCH  256      // HHH*DDD
#define NINP 8
#define NOUTP 128
#define NLAY 10
#define SLOPE 0.2f
#define PCHUNK 32     // pool stage-1 chunks per graph

typedef short v8s  __attribute__((ext_vector_type(8)));
typedef float v4f  __attribute__((ext_vector_type(4)));

__device__ __forceinline__ float gelu_f(float x){
    return 0.5f * x * (1.0f + erff(x * 0.70710678118654752f));
}
__device__ __forceinline__ unsigned short f2bf(float f){
    unsigned u = __float_as_uint(f);
    unsigned r = u + 0x7FFF + ((u >> 16) & 1);   // RNE
    return (unsigned short)(r >> 16);
}
__device__ __forceinline__ float bf2f(unsigned short b){
    return __uint_as_float(((unsigned)b) << 16);
}
__device__ __forceinline__ float lrelu(float e){
    return (e > 0.f) ? e : SLOPE * e;
}
__device__ __forceinline__ unsigned pack2(float a, float b){
    return (unsigned)f2bf(a) | ((unsigned)f2bf(b) << 16);
}
// unpack 4 bf16 (little-endian packed in uint2) -> float4
__device__ __forceinline__ float4 up4(uint2 u){
    float4 r;
    r.x = __uint_as_float(u.x << 16);
    r.y = __uint_as_float(u.x & 0xFFFF0000u);
    r.z = __uint_as_float(u.y << 16);
    r.w = __uint_as_float(u.y & 0xFFFF0000u);
    return r;
}

// ---------------- CSR build ----------------
__global__ void count_k(const int* __restrict__ ei, int* __restrict__ cnt){
    int e = blockIdx.x * 256 + threadIdx.x;
    if (e >= ETOT) return;
    int d = (e < EE) ? ei[EE + e] : (e - EE);
    atomicAdd(&cnt[d], 1);
}

// single block, 1024 thr, 30 elems/thread in registers; 2 barriers total
__global__ __launch_bounds__(1024) void scan_k(const int* __restrict__ cnt, int* __restrict__ row_ptr){
    const int PER = 30;                 // 1024*30 = 30720 >= NN
    int t = threadIdx.x;
    int base = t * PER;
    int v[PER];
    int sum = 0;
#pragma unroll
    for (int i = 0; i < PER; ++i){
        int x = (base + i < NN) ? cnt[base + i] : 0;
        v[i] = sum;                     // exclusive prefix within thread
        sum += x;
    }
    int lane = t & 63, w = t >> 6;
    int inc = sum;
#pragma unroll
    for (int off = 1; off < 64; off <<= 1){
        int u = __shfl_up(inc, off);
        if (lane >= off) inc += u;
    }
    __shared__ int wtot[16], woff[16];
    if (lane == 63) wtot[w] = inc;
    __syncthreads();
    if (t == 0){
        int r = 0;
        for (int i = 0; i < 16; ++i){ woff[i] = r; r += wtot[i]; }
        row_ptr[NN] = r;
    }
    __syncthreads();
    int excl = woff[w] + (inc - sum);
#pragma unroll
    for (int i = 0; i < PER; ++i){
        if (base + i < NN) row_ptr[base + i] = excl + v[i];
    }
}

__global__ void scatter_k(const int* __restrict__ ei, const int* __restrict__ row_ptr,
                          int* __restrict__ cursor, int* __restrict__ csr_src){
    int e = blockIdx.x * 256 + threadIdx.x;
    if (e >= ETOT) return;
    int s, d;
    if (e < EE){ s = ei[e]; d = ei[EE + e]; } else { s = d = e - EE; }
    int pos = row_ptr[d] + atomicAdd(&cursor[d], 1);
    csr_src[pos] = s;
}

// ---------------- weight prep: 32x32 LDS tile transpose + bf16 hi/lo split ----------------
__global__ __launch_bounds__(256) void wconv_k(const float* __restrict__ Ws,
                                               unsigned short* __restrict__ WT_hi,
                                               unsigned short* __restrict__ WT_lo){
    __shared__ float tile[32][33];
    int l = blockIdx.x;
    int kt = (blockIdx.y >> 3) * 32;
    int nt = (blockIdx.y & 7) * 32;
    const float* W = Ws + (size_t)l * CCH * CCH;
    unsigned short* th = WT_hi + (size_t)l * CCH * CCH;
    unsigned short* tl = WT_lo + (size_t)l * CCH * CCH;
    int tx = threadIdx.x & 31, ty = threadIdx.x >> 5;
#pragma unroll
    for (int r = ty; r < 32; r += 8)
        tile[r][tx] = W[(size_t)(kt + r) * CCH + nt + tx];
    __syncthreads();
#pragma unroll
    for (int r = ty; r < 32; r += 8){
        float w = tile[tx][r];          // = W[kt+tx][nt+r]
        unsigned short h = f2bf(w);
        size_t o = (size_t)(nt + r) * CCH + kt + tx;
        th[o] = h;
        tl[o] = f2bf(w - bf2f(h));
    }
}

// ---------------- alpha-weight prep: grid (NLAY-1, 8) ----------------
__global__ __launch_bounds__(256) void waconv_k(const float* __restrict__ Ws,
                                                const float* __restrict__ a_srcs,
                                                const float* __restrict__ a_dsts,
                                                unsigned short* __restrict__ wa_hi,
                                                unsigned short* __restrict__ wa_lo){
    int l = blockIdx.x;
    int j = blockIdx.y;
    int k = threadIdx.x;
    const float* W = Ws + (size_t)l * CCH * CCH;
    const float* av = (j < 4) ? (a_srcs + (size_t)l * CCH + j * DDD)
                              : (a_dsts + (size_t)l * CCH + (j - 4) * DDD);
    int cb = (j & 3) * DDD;
    float s = 0.f;
    const float4* wp = (const float4*)(W + (size_t)k * CCH + cb);
    const float4* ap = (const float4*)av;
#pragma unroll
    for (int d = 0; d < DDD / 4; ++d){
        float4 wv = wp[d], avv = ap[d];
        s += wv.x * avv.x + wv.y * avv.y + wv.z * avv.z + wv.w * avv.w;
    }
    unsigned short hb = f2bf(s);
    wa_hi[((size_t)l * 16 + j) * CCH + k] = hb;
    wa_lo[((size_t)l * 16 + j) * CCH + k] = f2bf(s - bf2f(hb));
    if (j >= 4){  // zero the padding cols 8..15 (two per block)
        wa_hi[((size_t)l * 16 + j + 4) * CCH + k] = 0;
        wa_lo[((size_t)l * 16 + j + 4) * CCH + k] = 0;
        wa_hi[((size_t)l * 16 + j + 8) * CCH + k] = 0;
        wa_lo[((size_t)l * 16 + j + 8) * CCH + k] = 0;
    }
}

// ---------------- layer 0 fused: grid-stride, W0 column registered once ----------------
__global__ __launch_bounds__(256) void l0_fused(const float* __restrict__ x,
                                                const float* __restrict__ W0,
                                                const float* __restrict__ a_src,
                                                const float* __restrict__ a_dst,
                                                unsigned short* __restrict__ hout,
                                                float* __restrict__ asb,
                                                float* __restrict__ adb){
    __shared__ float xs[NINP];
    int c = threadIdx.x;
    float w0[NINP];
#pragma unroll
    for (int k = 0; k < NINP; ++k) w0[k] = W0[k * CCH + c];
    int hh = c >> 6, lane = c & 63;
    float asv = a_src[hh * DDD + lane];
    float adv = a_dst[hh * DDD + lane];
    for (int n = blockIdx.x; n < NN; n += gridDim.x){
        if (c < NINP) xs[c] = x[n * NINP + c];
        __syncthreads();
        float acc = 0.f;
#pragma unroll
        for (int k = 0; k < NINP; ++k) acc += xs[k] * w0[k];
        hout[(size_t)n * CCH + c] = f2bf(acc);
        float s1 = acc * asv;
        float s2 = acc * adv;
#pragma unroll
        for (int off = 32; off; off >>= 1){
            s1 += __shfl_xor(s1, off);
            s2 += __shfl_xor(s2, off);
        }
        if (lane == 0){
            asb[(size_t)n * HHH + hh] = s1;
            adb[(size_t)n * HHH + hh] = s2;
        }
        __syncthreads();
    }
}

// ---------------- main GEMM: 64x128 tile, 4 waves x (64 rows x 32 cols) ----------------
// A bf16 pre-gelu'd; 2 MFMA products (a*Whi + a*Wlo). A-tile per block = 32 KB (~L1).
// grid (2, 469) = 938 blocks -> ~3.7 blocks/CU for latency hiding.
__global__ __launch_bounds__(256) void gemm_mfma(const unsigned short* __restrict__ A,
                                                 const unsigned short* __restrict__ Bhi,
                                                 const unsigned short* __restrict__ Blo,
                                                 const unsigned short* __restrict__ WAhi,
                                                 const unsigned short* __restrict__ WAlo,
                                                 unsigned short* __restrict__ C,
                                                 float* __restrict__ asb,
                                                 float* __restrict__ adb){
    int tid  = threadIdx.x;
    int lane = tid & 63, wave = tid >> 6;
    int rowBase = blockIdx.y * 64;
    int colBase = blockIdx.x * 128 + wave * 32;
    int fr = lane & 15;      // fragment row (A) / col (B,D)
    int kg = lane >> 4;      // k-group 0..3
    bool doAlpha = (blockIdx.x == 0) && (wave == 0);

    v4f acc[4][2];
#pragma unroll
    for (int mi = 0; mi < 4; ++mi)
#pragma unroll
        for (int ni = 0; ni < 2; ++ni) acc[mi][ni] = (v4f){0.f, 0.f, 0.f, 0.f};
    v4f acca[4];
#pragma unroll
    for (int mi = 0; mi < 4; ++mi) acca[mi] = (v4f){0.f, 0.f, 0.f, 0.f};

    const unsigned short* aptr[4];
#pragma unroll
    for (int mi = 0; mi < 4; ++mi){
        int r = rowBase + mi * 16 + fr;
        if (r >= NN) r = NN - 1;                  // clamp; stores guarded below
        aptr[mi] = A + (size_t)r * CCH + kg * 8;
    }
    const unsigned short* bhp[2];
    const unsigned short* blp[2];
#pragma unroll
    for (int ni = 0; ni < 2; ++ni){
        int c = colBase + ni * 16 + fr;
        bhp[ni] = Bhi + (size_t)c * CCH + kg * 8;
        blp[ni] = Blo + (size_t)c * CCH + kg * 8;
    }
    const unsigned short* wahp = WAhi + (size_t)fr * CCH + kg * 8;
    const unsigned short* walp = WAlo + (size_t)fr * CCH + kg * 8;

    for (int kc = 0; kc < CCH; kc += 32){
        v8s a[4], bh[2], bl[2];
#pragma unroll
        for (int mi = 0; mi < 4; ++mi) a[mi] = *(const v8s*)(aptr[mi] + kc);
#pragma unroll
        for (int ni = 0; ni < 2; ++ni){
            bh[ni] = *(const v8s*)(bhp[ni] + kc);
            bl[ni] = *(const v8s*)(blp[ni] + kc);
        }
#pragma unroll
        for (int mi = 0; mi < 4; ++mi)
#pragma unroll
            for (int ni = 0; ni < 2; ++ni){
                acc[mi][ni] = __builtin_amdgcn_mfma_f32_16x16x32_bf16(a[mi], bh[ni], acc[mi][ni], 0, 0, 0);
                acc[mi][ni] = __builtin_amdgcn_mfma_f32_16x16x32_bf16(a[mi], bl[ni], acc[mi][ni], 0, 0, 0);
            }
        if (doAlpha){
            v8s wh = *(const v8s*)(wahp + kc);
            v8s wl = *(const v8s*)(walp + kc);
#pragma unroll
            for (int mi = 0; mi < 4; ++mi){
                acca[mi] = __builtin_amdgcn_mfma_f32_16x16x32_bf16(a[mi], wh, acca[mi], 0, 0, 0);
                acca[mi] = __builtin_amdgcn_mfma_f32_16x16x32_bf16(a[mi], wl, acca[mi], 0, 0, 0);
            }
        }
    }

    // D layout: col = lane&15 (=fr), row = (lane>>4)*4 + j (=kg*4+j)
#pragma unroll
    for (int mi = 0; mi < 4; ++mi)
#pragma unroll
        for (int j = 0; j < 4; ++j){
            int r = rowBase + mi * 16 + kg * 4 + j;
            if (r < NN){
#pragma unroll
                for (int ni = 0; ni < 2; ++ni)
                    C[(size_t)r * CCH + colBase + ni * 16 + fr] = f2bf(acc[mi][ni][j]);
            }
        }
    if (doAlpha){
#pragma unroll
        for (int mi = 0; mi < 4; ++mi)
#pragma unroll
            for (int j = 0; j < 4; ++j){
                int r = rowBase + mi * 16 + kg * 4 + j;
                if (r < NN){
                    float val = acca[mi][j];
                    if (fr < 4)      asb[(size_t)r * HHH + fr]       = val;
                    else if (fr < 8) adb[(size_t)r * HHH + (fr - 4)] = val;
                }
            }
    }
}

// ---------------- per-node softmax + aggregation: ONE WAVE PER NODE ----------------
// Fast path (deg<=64): no-max softmax; edge list PADDED to a multiple of 8
// (idx=self, alpha=0) so the entire gather runs through the 2-slot pipeline —
// no serial remainder loop. mode 0: bf16(gelu(acc+bias)); mode 1: fp32.
#define LOADG8(gg, U0, U1, U2, U3, A0, A1, A2, A3)                     \
    { int _b = (gg) << 3;                                              \
      int _e0 = _b + half, _e1 = _b + 2 + half;                        \
      int _e2 = _b + 4 + half, _e3 = _b + 6 + half;                    \
      int _i0 = ix_w[_e0], _i1 = ix_w[_e1];                            \
      int _i2 = ix_w[_e2], _i3 = ix_w[_e3];                            \
      A0 = al_w[_e0 * HHH + hc8];                                      \
      A1 = al_w[_e1 * HHH + hc8];                                      \
      A2 = al_w[_e2 * HHH + hc8];                                      \
      A3 = al_w[_e3 * HHH + hc8];                                      \
      U0 = *(const uint4*)(h + (size_t)_i0 * CCH + coff8);             \
      U1 = *(const uint4*)(h + (size_t)_i1 * CCH + coff8);             \
      U2 = *(const uint4*)(h + (size_t)_i2 * CCH + coff8);             \
      U3 = *(const uint4*)(h + (size_t)_i3 * CCH + coff8); }

#define CONSUME8(U0, U1, U2, U3, A0, A1, A2, A3)                       \
    { float4 _l0 = up4(make_uint2(U0.x, U0.y)), _h0 = up4(make_uint2(U0.z, U0.w)); \
      float4 _l1 = up4(make_uint2(U1.x, U1.y)), _h1 = up4(make_uint2(U1.z, U1.w)); \
      float4 _l2 = up4(make_uint2(U2.x, U2.y)), _h2 = up4(make_uint2(U2.z, U2.w)); \
      float4 _l3 = up4(make_uint2(U3.x, U3.y)), _h3 = up4(make_uint2(U3.z, U3.w)); \
      accLo.x += _l0.x * A0 + _l1.x * A1 + _l2.x * A2 + _l3.x * A3;    \
      accLo.y += _l0.y * A0 + _l1.y * A1 + _l2.y * A2 + _l3.y * A3;    \
      accLo.z += _l0.z * A0 + _l1.z * A1 + _l2.z * A2 + _l3.z * A3;    \
      accLo.w += _l0.w * A0 + _l1.w * A1 + _l2.w * A2 + _l3.w * A3;    \
      accHi.x += _h0.x * A0 + _h1.x * A1 + _h2.x * A2 + _h3.x * A3;    \
      accHi.y += _h0.y * A0 + _h1.y * A1 + _h2.y * A2 + _h3.y * A3;    \
      accHi.z += _h0.z * A0 + _h1.z * A1 + _h2.z * A2 + _h3.z * A3;    \
      accHi.w += _h0.w * A0 + _h1.w * A1 + _h2.w * A2 + _h3.w * A3; }

__global__ __launch_bounds__(256) void agg_k(const unsigned short* __restrict__ h,
                                             const float* __restrict__ asrc,
                                             const float* __restrict__ adst,
                                             const float* __restrict__ bias,
                                             const int* __restrict__ row_ptr,
                                             const int* __restrict__ csr_src,
                                             unsigned short* __restrict__ outg,
                                             float* __restrict__ outf,
                                             int mode){
    __shared__ float s_al[4][64 * HHH];
    __shared__ int   s_ix[4][64];

    int wave = threadIdx.x >> 6, lane = threadIdx.x & 63;
    int n = blockIdx.x * 4 + wave;
    int row0 = row_ptr[n];
    int deg  = row_ptr[n + 1] - row0;
    float4 ad = *(const float4*)(adst + (size_t)n * HHH);
    float* al_w = s_al[wave];
    int*   ix_w = s_ix[wave];

    if (deg <= 64){
        // ---- phase 1: lane k = edge k, no-max shuffle softmax ----
        int k = lane;
        int padDeg = (deg + 7) & ~7;
        int s = 0;
        float x0 = 0.f, x1 = 0.f, x2 = 0.f, x3 = 0.f;
        if (k < deg){
            s = csr_src[row0 + k];
            float4 as = *(const float4*)(asrc + (size_t)s * HHH);
            x0 = __expf(lrelu(as.x + ad.x)); x1 = __expf(lrelu(as.y + ad.y));
            x2 = __expf(lrelu(as.z + ad.z)); x3 = __expf(lrelu(as.w + ad.w));
        }
        float z0 = x0, z1 = x1, z2 = x2, z3 = x3;
#pragma unroll
        for (int off = 32; off; off >>= 1){
            z0 += __shfl_xor(z0, off);
            z1 += __shfl_xor(z1, off);
            z2 += __shfl_xor(z2, off);
            z3 += __shfl_xor(z3, off);
        }
        if (k < deg){
            float4 alv;
            alv.x = x0 / (z0 + 1e-16f);
            alv.y = x1 / (z1 + 1e-16f);
            alv.z = x2 / (z2 + 1e-16f);
            alv.w = x3 / (z3 + 1e-16f);
            ix_w[k] = s;
            *(float4*)&al_w[k * HHH] = alv;
        } else if (k < padDeg){
            ix_w[k] = n;                                // self row: always valid
            *(float4*)&al_w[k * HHH] = make_float4(0.f, 0.f, 0.f, 0.f);
        }
        // ---- phase 2: half-wave dwordx4 gather, fully pipelined (no remainder) ----
        int half  = lane >> 5;
        int l32   = lane & 31;
        int coff8 = l32 << 3;        // 8 channels per lane
        int hc8   = l32 >> 3;        // head of those channels
        float4 accLo = make_float4(0.f, 0.f, 0.f, 0.f);
        float4 accHi = make_float4(0.f, 0.f, 0.f, 0.f);

        int ng = padDeg >> 3;        // groups of 8 edges (exact after padding)
        uint4 uA0, uA1, uA2, uA3, uB0, uB1, uB2, uB3;
        float aA0, aA1, aA2, aA3, aB0, aB1, aB2, aB3;
        if (ng > 0) LOADG8(0, uA0, uA1, uA2, uA3, aA0, aA1, aA2, aA3);
        if (ng > 1) LOADG8(1, uB0, uB1, uB2, uB3, aB0, aB1, aB2, aB3);
        for (int g = 0; g < ng; g += 2){
            if (g + 2 < ng) {
                CONSUME8(uA0, uA1, uA2, uA3, aA0, aA1, aA2, aA3);
                LOADG8(g + 2, uA0, uA1, uA2, uA3, aA0, aA1, aA2, aA3);
            } else {
                CONSUME8(uA0, uA1, uA2, uA3, aA0, aA1, aA2, aA3);
            }
            if (g + 1 < ng){
                if (g + 3 < ng) {
                    CONSUME8(uB0, uB1, uB2, uB3, aB0, aB1, aB2, aB3);
                    LOADG8(g + 3, uB0, uB1, uB2, uB3, aB0, aB1, aB2, aB3);
                } else {
                    CONSUME8(uB0, uB1, uB2, uB3, aB0, aB1, aB2, aB3);
                }
            }
        }
        // combine halves
        accLo.x += __shfl_xor(accLo.x, 32); accLo.y += __shfl_xor(accLo.y, 32);
        accLo.z += __shfl_xor(accLo.z, 32); accLo.w += __shfl_xor(accLo.w, 32);
        accHi.x += __shfl_xor(accHi.x, 32); accHi.y += __shfl_xor(accHi.y, 32);
        accHi.z += __shfl_xor(accHi.z, 32); accHi.w += __shfl_xor(accHi.w, 32);
        if (half == 0){
            float4 b0v = *(const float4*)(bias + coff8);
            float4 b1v = *(const float4*)(bias + coff8 + 4);
            accLo.x += b0v.x; accLo.y += b0v.y; accLo.z += b0v.z; accLo.w += b0v.w;
            accHi.x += b1v.x; accHi.y += b1v.y; accHi.z += b1v.z; accHi.w += b1v.w;
            if (mode == 0){
                uint4 o;
                o.x = pack2(gelu_f(accLo.x), gelu_f(accLo.y));
                o.y = pack2(gelu_f(accLo.z), gelu_f(accLo.w));
                o.z = pack2(gelu_f(accHi.x), gelu_f(accHi.y));
                o.w = pack2(gelu_f(accHi.z), gelu_f(accHi.w));
                *(uint4*)(outg + (size_t)n * CCH + coff8) = o;
            } else {
                *(float4*)(outf + (size_t)n * CCH + coff8)     = accLo;
                *(float4*)(outf + (size_t)n * CCH + coff8 + 4) = accHi;
            }
        }
        return;
    }

    // ---- generic path: online softmax over 64-edge chunks (uint2 gather) ----
    int coff = lane << 2;
    int hc   = lane >> 4;
    float4 acc = make_float4(0.f, 0.f, 0.f, 0.f);
    float m0 = -INFINITY, m1 = -INFINITY, m2 = -INFINITY, m3 = -INFINITY;
    float z0 = 0.f, z1 = 0.f, z2 = 0.f, z3 = 0.f;
    for (int c0 = 0; c0 < deg; c0 += 64){
        int k = c0 + lane;
        float e0 = -INFINITY, e1 = -INFINITY, e2 = -INFINITY, e3 = -INFINITY;
        if (k < deg){
            int s = csr_src[row0 + k];
            float4 as = *(const float4*)(asrc + (size_t)s * HHH);
            e0 = lrelu(as.x + ad.x); e1 = lrelu(as.y + ad.y);
            e2 = lrelu(as.z + ad.z); e3 = lrelu(as.w + ad.w);
        }
        float c0m = e0, c1m = e1, c2m = e2, c3m = e3;
#pragma unroll
        for (int off = 32; off; off >>= 1){
            c0m = fmaxf(c0m, __shfl_xor(c0m, off));
            c1m = fmaxf(c1m, __shfl_xor(c1m, off));
            c2m = fmaxf(c2m, __shfl_xor(c2m, off));
            c3m = fmaxf(c3m, __shfl_xor(c3m, off));
        }
        float n0 = fmaxf(m0, c0m), n1 = fmaxf(m1, c1m);
        float n2 = fmaxf(m2, c2m), n3 = fmaxf(m3, c3m);
        float x0 = 0.f, x1 = 0.f, x2 = 0.f, x3 = 0.f;
        if (k < deg){
            x0 = __expf(e0 - n0); x1 = __expf(e1 - n1);
            x2 = __expf(e2 - n2); x3 = __expf(e3 - n3);
        }
        float s0 = x0, s1 = x1, s2 = x2, s3 = x3;
#pragma unroll
        for (int off = 32; off; off >>= 1){
            s0 += __shfl_xor(s0, off);
            s1 += __shfl_xor(s1, off);
            s2 += __shfl_xor(s2, off);
            s3 += __shfl_xor(s3, off);
        }
        z0 = z0 * ((m0 == -INFINITY) ? 0.f : __expf(m0 - n0)) + s0;
        z1 = z1 * ((m1 == -INFINITY) ? 0.f : __expf(m1 - n1)) + s1;
        z2 = z2 * ((m2 == -INFINITY) ? 0.f : __expf(m2 - n2)) + s2;
        z3 = z3 * ((m3 == -INFINITY) ? 0.f : __expf(m3 - n3)) + s3;
        m0 = n0; m1 = n1; m2 = n2; m3 = n3;
    }
    float iz0 = 1.f / (z0 + 1e-16f), iz1 = 1.f / (z1 + 1e-16f);
    float iz2 = 1.f / (z2 + 1e-16f), iz3 = 1.f / (z3 + 1e-16f);
    for (int c0 = 0; c0 < deg; c0 += 64){
        int k = c0 + lane;
        if (k < deg){
            int s = csr_src[row0 + k];
            float4 as = *(const float4*)(asrc + (size_t)s * HHH);
            float4 alv;
            alv.x = __expf(lrelu(as.x + ad.x) - m0) * iz0;
            alv.y = __expf(lrelu(as.y + ad.y) - m1) * iz1;
            alv.z = __expf(lrelu(as.z + ad.z) - m2) * iz2;
            alv.w = __expf(lrelu(as.w + ad.w) - m3) * iz3;
            ix_w[lane] = s;
            *(float4*)&al_w[lane * HHH] = alv;
        }
        int cnt = deg - c0; if (cnt > 64) cnt = 64;
        for (int j = 0; j < cnt; ++j){
            int i0 = ix_w[j];
            float a0 = al_w[j * HHH + hc];
            float4 v0 = up4(*(const uint2*)(h + (size_t)i0 * CCH + coff));
            acc.x += v0.x * a0; acc.y += v0.y * a0; acc.z += v0.z * a0; acc.w += v0.w * a0;
        }
    }
    float4 bv = *(const float4*)(bias + coff);
    acc.x += bv.x; acc.y += bv.y; acc.z += bv.z; acc.w += bv.w;
    if (mode == 0){
        uint2 o;
        o.x = pack2(gelu_f(acc.x), gelu_f(acc.y));
        o.y = pack2(gelu_f(acc.z), gelu_f(acc.w));
        *(uint2*)(outg + (size_t)n * CCH + coff) = o;
    } else {
        *(float4*)(outf + (size_t)n * CCH + coff) = acc;
    }
}

// ---------------- graph boundary pointers (batch is sorted) ----------------
__global__ void gptr_k(const int* __restrict__ batch, int* __restrict__ gptr){
    int i = blockIdx.x * 256 + threadIdx.x;
    if (i >= NN) return;
    int bi = batch[i];
    int bp = (i == 0) ? -1 : batch[i - 1];
    for (int g = bp + 1; g <= bi; ++g) gptr[g] = i;
    if (i == NN - 1){
        for (int g = bi + 1; g <= BB; ++g) gptr[g] = NN;
    }
}

// ---------------- pooling stage 1 ----------------
__global__ __launch_bounds__(256) void pool1_k(const float* __restrict__ h,
                                               const int* __restrict__ gptr,
                                               float* __restrict__ part){
    const int S1 = BB * PCHUNK * CCH;
    int b = blockIdx.x, j = blockIdx.y, c = threadIdx.x;
    int s = gptr[b], e = gptr[b + 1];
    int len = e - s;
    int per = (len + PCHUNK - 1) / PCHUNK;
    int r0 = s + j * per;
    int r1 = r0 + per; if (r1 > e) r1 = e;
    float mn = INFINITY, mx = -INFINITY, sm = 0.f;
    int n = r0;
    for (; n + 4 <= r1; n += 4){
        float v0 = h[(size_t)(n + 0) * CCH + c];
        float v1 = h[(size_t)(n + 1) * CCH + c];
        float v2 = h[(size_t)(n + 2) * CCH + c];
        float v3 = h[(size_t)(n + 3) * CCH + c];
        mn = fminf(mn, fminf(fminf(v0, v1), fminf(v2, v3)));
        mx = fmaxf(mx, fmaxf(fmaxf(v0, v1), fmaxf(v2, v3)));
        sm += (v0 + v1) + (v2 + v3);
    }
    for (; n < r1; ++n){
        float v = h[(size_t)n * CCH + c];
        mn = fminf(mn, v); mx = fmaxf(mx, v); sm += v;
    }
    size_t o = ((size_t)b * PCHUNK + j) * CCH + c;
    part[o] = mn; part[S1 + o] = mx; part[2 * (size_t)S1 + o] = sm;
}

// ---------------- pooling stage 2 ----------------
__global__ __launch_bounds__(256) void pool2_k(const float* __restrict__ part,
                                               const int* __restrict__ gptr,
                                               float* __restrict__ gbuf){
    const int S1 = BB * PCHUNK * CCH;
    int b = blockIdx.x, c = threadIdx.x;
    float mn = INFINITY, mx = -INFINITY, sm = 0.f;
#pragma unroll
    for (int j = 0; j < PCHUNK; ++j){
        size_t o = ((size_t)b * PCHUNK + j) * CCH + c;
        mn = fminf(mn, part[o]);
        mx = fmaxf(mx, part[S1 + o]);
        sm += part[2 * (size_t)S1 + o];
    }
    int cnt = gptr[b + 1] - gptr[b];
    float mean = sm / fmaxf((float)cnt, 1.0f);
    if (cnt == 0){ mn = 0.f; mx = 0.f; }
    gbuf[b * 4 * CCH + 0 * CCH + c] = mn;
    gbuf[b * 4 * CCH + 1 * CCH + c] = mx;
    gbuf[b * 4 * CCH + 2 * CCH + c] = mean;
    gbuf[b * 4 * CCH + 3 * CCH + c] = sm;
}

// ---------------- head: gelu(g) @ head_W + head_b ----------------
__global__ __launch_bounds__(128) void head_k(const float* __restrict__ gbuf,
                                              const float* __restrict__ head_W,
                                              const float* __restrict__ head_b,
                                              float* __restrict__ out){
    __shared__ float gs[4 * CCH];
    int b = blockIdx.x;
    int o = threadIdx.x;
    for (int k = o; k < 4 * CCH; k += 128) gs[k] = gelu_f(gbuf[b * 4 * CCH + k]);
    __syncthreads();
    float acc = head_b[o];
    for (int k = 0; k < 4 * CCH; ++k) acc += gs[k] * head_W[k * NOUTP + o];
    out[b * NOUTP + o] = acc;
}

extern "C" void kernel_launch(void* const* d_in, const int* in_sizes, int n_in,
                              void* d_out, int out_size, void* d_ws, size_t ws_size,
                              hipStream_t stream){
    const float* x        = (const float*)d_in[0];
    const int*   ei       = (const int*)  d_in[1];
    const int*   batch    = (const int*)  d_in[2];
    const float* W0       = (const float*)d_in[3];
    const float* a_src0   = (const float*)d_in[4];
    const float* a_dst0   = (const float*)d_in[5];
    const float* b0       = (const float*)d_in[6];
    const float* Ws       = (const float*)d_in[7];
    const float* a_srcs   = (const float*)d_in[8];
    const float* a_dsts   = (const float*)d_in[9];
    const float* bs       = (const float*)d_in[10];
    const float* head_W   = (const float*)d_in[11];
    const float* head_b   = (const float*)d_in[12];
    float* out = (float*)d_out;

    char* p = (char*)d_ws;
    float* buf0f = (float*)p;                   p += (size_t)NN * CCH * 4;   // fp32 final agg (pooling)
    unsigned short* buf0g = (unsigned short*)p; p += (size_t)NN * CCH * 2;   // bf16 gelu'd agg (gemm A)
    unsigned short* buf1  = (unsigned short*)p; p += (size_t)NN * CCH * 2;   // bf16 payload h_l
    float* asb  = (float*)p;                   p += (size_t)NN * HHH * 4;
    float* adb  = (float*)p;                   p += (size_t)NN * HHH * 4;
    int* row_ptr = (int*)p;                    p += 120016;                 // (N+1)*4 padded
    int* cnt     = (int*)p;                    p += (size_t)NN * 4;
    int* csr_src = (int*)p;                    p += (size_t)ETOT * 4;
    float* gbuf  = (float*)p;                  p += (size_t)BB * 4 * CCH * 4;
    int* gptr    = (int*)p;                    p += 208;
    unsigned short* wthi = (unsigned short*)p; p += (size_t)(NLAY - 1) * CCH * CCH * 2;
    unsigned short* wtlo = (unsigned short*)p; p += (size_t)(NLAY - 1) * CCH * CCH * 2;
    unsigned short* wahi = (unsigned short*)p; p += (size_t)(NLAY - 1) * 16 * CCH * 2;
    unsigned short* walo = (unsigned short*)p; p += (size_t)(NLAY - 1) * 16 * CCH * 2;
    float* pscr = (float*)p;                   p += (size_t)3 * BB * PCHUNK * CCH * 4;  // pool partials

    // ---- CSR build + weight prep ----
    hipMemsetAsync(cnt, 0, (size_t)NN * 4, stream);
    count_k<<<(ETOT + 255) / 256, 256, 0, stream>>>(ei, cnt);
    scan_k<<<1, 1024, 0, stream>>>(cnt, row_ptr);
    hipMemsetAsync(cnt, 0, (size_t)NN * 4, stream);
    scatter_k<<<(ETOT + 255) / 256, 256, 0, stream>>>(ei, row_ptr, cnt, csr_src);
    gptr_k<<<(NN + 255) / 256, 256, 0, stream>>>(batch, gptr);
    wconv_k<<<dim3(NLAY - 1, 64), 256, 0, stream>>>(Ws, wthi, wtlo);
    waconv_k<<<dim3(NLAY - 1, 8), 256, 0, stream>>>(Ws, a_srcs, a_dsts, wahi, walo);

    // ---- layer 0 (fused h0 + alpha, grid-stride) ----
    l0_fused<<<512, 256, 0, stream>>>(x, W0, a_src0, a_dst0, buf1, asb, adb);
    agg_k<<<NN / 4, 256, 0, stream>>>(buf1, asb, adb, b0, row_ptr, csr_src,
                                      buf0g, buf0f, 0);

    // ---- layers 1..9 (alpha fused into gemm; A is bf16 gelu'd) ----
    dim3 ggrid(2, (NN + 63) / 64);
    for (int l = 1; l < NLAY; ++l){
        const unsigned short* whl = wthi + (size_t)(l - 1) * CCH * CCH;
        const unsigned short* wll = wtlo + (size_t)(l - 1) * CCH * CCH;
        const unsigned short* wal_h = wahi + (size_t)(l - 1) * 16 * CCH;
        const unsigned short* wal_l = walo + (size_t)(l - 1) * 16 * CCH;
        const float* bl  = bs + (size_t)(l - 1) * CCH;
        gemm_mfma<<<ggrid, 256, 0, stream>>>(buf0g, whl, wll, wal_h, wal_l, buf1, asb, adb);
        agg_k<<<NN / 4, 256, 0, stream>>>(buf1, asb, adb, bl, row_ptr, csr_src,
                                          buf0g, buf0f, (l == NLAY - 1) ? 1 : 0);
    }

    // ---- readout ----
    dim3 pgrid(BB, PCHUNK);
    pool1_k<<<pgrid, 256, 0, stream>>>(buf0f, gptr, pscr);
    pool2_k<<<BB, 256, 0, stream>>>(pscr, gptr, gbuf);
    head_k<<<BB, 128, 0, stream>>>(gbuf, head_W, head_b, out);
}

// Round 12
// 960.958 us; speedup vs baseline: 1.0302x; 1.0302x over previous
//
#include <hip/hip_runtime.h>
#include <math.h>

#define NN   30000
#define EE   480000
#define ETOT 510000   // EE + NN self loops
#define BB   48
#define HHH  4
#define DDD  64
#define CCH  256      // HHH*DDD
#define NINP 8
#define NOUTP 128
#define NLAY 10
#define SLOPE 0.2f
#define PCHUNK 32     // pool stage-1 chunks per graph

typedef short v8s  __attribute__((ext_vector_type(8)));
typedef float v4f  __attribute__((ext_vector_type(4)));

__device__ __forceinline__ float gelu_f(float x){
    return 0.5f * x * (1.0f + erff(x * 0.70710678118654752f));
}
__device__ __forceinline__ unsigned short f2bf(float f){
    unsigned u = __float_as_uint(f);
    unsigned r = u + 0x7FFF + ((u >> 16) & 1);   // RNE
    return (unsigned short)(r >> 16);
}
__device__ __forceinline__ float bf2f(unsigned short b){
    return __uint_as_float(((unsigned)b) << 16);
}
__device__ __forceinline__ float lrelu(float e){
    return (e > 0.f) ? e : SLOPE * e;
}
__device__ __forceinline__ unsigned pack2(float a, float b){
    return (unsigned)f2bf(a) | ((unsigned)f2bf(b) << 16);
}
// unpack 4 bf16 (little-endian packed in uint2) -> float4
__device__ __forceinline__ float4 up4(uint2 u){
    float4 r;
    r.x = __uint_as_float(u.x << 16);
    r.y = __uint_as_float(u.x & 0xFFFF0000u);
    r.z = __uint_as_float(u.y << 16);
    r.w = __uint_as_float(u.y & 0xFFFF0000u);
    return r;
}

// ---------------- CSR build ----------------
__global__ void count_k(const int* __restrict__ ei, int* __restrict__ cnt){
    int e = blockIdx.x * 256 + threadIdx.x;
    if (e >= ETOT) return;
    int d = (e < EE) ? ei[EE + e] : (e - EE);
    atomicAdd(&cnt[d], 1);
}

// single block, 1024 thr, 30 elems/thread in registers; 2 barriers total
__global__ __launch_bounds__(1024) void scan_k(const int* __restrict__ cnt, int* __restrict__ row_ptr){
    const int PER = 30;                 // 1024*30 = 30720 >= NN
    int t = threadIdx.x;
    int base = t * PER;
    int v[PER];
    int sum = 0;
#pragma unroll
    for (int i = 0; i < PER; ++i){
        int x = (base + i < NN) ? cnt[base + i] : 0;
        v[i] = sum;                     // exclusive prefix within thread
        sum += x;
    }
    int lane = t & 63, w = t >> 6;
    int inc = sum;
#pragma unroll
    for (int off = 1; off < 64; off <<= 1){
        int u = __shfl_up(inc, off);
        if (lane >= off) inc += u;
    }
    __shared__ int wtot[16], woff[16];
    if (lane == 63) wtot[w] = inc;
    __syncthreads();
    if (t == 0){
        int r = 0;
        for (int i = 0; i < 16; ++i){ woff[i] = r; r += wtot[i]; }
        row_ptr[NN] = r;
    }
    __syncthreads();
    int excl = woff[w] + (inc - sum);
#pragma unroll
    for (int i = 0; i < PER; ++i){
        if (base + i < NN) row_ptr[base + i] = excl + v[i];
    }
}

__global__ void scatter_k(const int* __restrict__ ei, const int* __restrict__ row_ptr,
                          int* __restrict__ cursor, int* __restrict__ csr_src){
    int e = blockIdx.x * 256 + threadIdx.x;
    if (e >= ETOT) return;
    int s, d;
    if (e < EE){ s = ei[e]; d = ei[EE + e]; } else { s = d = e - EE; }
    int pos = row_ptr[d] + atomicAdd(&cursor[d], 1);
    csr_src[pos] = s;
}

// ---------------- weight prep: 32x32 LDS tile transpose + bf16 hi/lo split ----------------
__global__ __launch_bounds__(256) void wconv_k(const float* __restrict__ Ws,
                                               unsigned short* __restrict__ WT_hi,
                                               unsigned short* __restrict__ WT_lo){
    __shared__ float tile[32][33];
    int l = blockIdx.x;
    int kt = (blockIdx.y >> 3) * 32;
    int nt = (blockIdx.y & 7) * 32;
    const float* W = Ws + (size_t)l * CCH * CCH;
    unsigned short* th = WT_hi + (size_t)l * CCH * CCH;
    unsigned short* tl = WT_lo + (size_t)l * CCH * CCH;
    int tx = threadIdx.x & 31, ty = threadIdx.x >> 5;
#pragma unroll
    for (int r = ty; r < 32; r += 8)
        tile[r][tx] = W[(size_t)(kt + r) * CCH + nt + tx];
    __syncthreads();
#pragma unroll
    for (int r = ty; r < 32; r += 8){
        float w = tile[tx][r];          // = W[kt+tx][nt+r]
        unsigned short h = f2bf(w);
        size_t o = (size_t)(nt + r) * CCH + kt + tx;
        th[o] = h;
        tl[o] = f2bf(w - bf2f(h));
    }
}

// ---------------- alpha-weight prep: grid (NLAY-1, 8) ----------------
__global__ __launch_bounds__(256) void waconv_k(const float* __restrict__ Ws,
                                                const float* __restrict__ a_srcs,
                                                const float* __restrict__ a_dsts,
                                                unsigned short* __restrict__ wa_hi,
                                                unsigned short* __restrict__ wa_lo){
    int l = blockIdx.x;
    int j = blockIdx.y;
    int k = threadIdx.x;
    const float* W = Ws + (size_t)l * CCH * CCH;
    const float* av = (j < 4) ? (a_srcs + (size_t)l * CCH + j * DDD)
                              : (a_dsts + (size_t)l * CCH + (j - 4) * DDD);
    int cb = (j & 3) * DDD;
    float s = 0.f;
    const float4* wp = (const float4*)(W + (size_t)k * CCH + cb);
    const float4* ap = (const float4*)av;
#pragma unroll
    for (int d = 0; d < DDD / 4; ++d){
        float4 wv = wp[d], avv = ap[d];
        s += wv.x * avv.x + wv.y * avv.y + wv.z * avv.z + wv.w * avv.w;
    }
    unsigned short hb = f2bf(s);
    wa_hi[((size_t)l * 16 + j) * CCH + k] = hb;
    wa_lo[((size_t)l * 16 + j) * CCH + k] = f2bf(s - bf2f(hb));
    if (j >= 4){  // zero the padding cols 8..15 (two per block)
        wa_hi[((size_t)l * 16 + j + 4) * CCH + k] = 0;
        wa_lo[((size_t)l * 16 + j + 4) * CCH + k] = 0;
        wa_hi[((size_t)l * 16 + j + 8) * CCH + k] = 0;
        wa_lo[((size_t)l * 16 + j + 8) * CCH + k] = 0;
    }
}

// ---------------- layer 0 fused: ONE WAVE PER NODE, no barriers ----------------
// Lane owns 4 channels; W0 rows are L1-resident (8 KB). Alpha projections via
// 4-round shfl_xor reduce within each 16-lane head group.
__global__ __launch_bounds__(256) void l0_fused(const float* __restrict__ x,
                                                const float* __restrict__ W0,
                                                const float* __restrict__ a_src,
                                                const float* __restrict__ a_dst,
                                                unsigned short* __restrict__ hout,
                                                float* __restrict__ asb,
                                                float* __restrict__ adb){
    int wave = threadIdx.x >> 6, lane = threadIdx.x & 63;
    int n = blockIdx.x * 4 + wave;
    if (n >= NN) return;
    int c0 = lane << 2;          // 4 channels [c0, c0+4)
    int hh = lane >> 4;          // head
    int dbase = (lane & 15) << 2;// channel-within-head base

    float xv[NINP];
#pragma unroll
    for (int k = 0; k < NINP; ++k) xv[k] = x[n * NINP + k];   // wave-uniform, L1 broadcast

    float4 acc = make_float4(0.f, 0.f, 0.f, 0.f);
#pragma unroll
    for (int k = 0; k < NINP; ++k){
        float4 w = *(const float4*)(W0 + k * CCH + c0);
        acc.x += xv[k] * w.x; acc.y += xv[k] * w.y;
        acc.z += xv[k] * w.z; acc.w += xv[k] * w.w;
    }
    uint2 o;
    o.x = pack2(acc.x, acc.y);
    o.y = pack2(acc.z, acc.w);
    *(uint2*)(hout + (size_t)n * CCH + c0) = o;

    float4 asv = *(const float4*)(a_src + hh * DDD + dbase);
    float4 adv = *(const float4*)(a_dst + hh * DDD + dbase);
    float s1 = acc.x * asv.x + acc.y * asv.y + acc.z * asv.z + acc.w * asv.w;
    float s2 = acc.x * adv.x + acc.y * adv.y + acc.z * adv.z + acc.w * adv.w;
#pragma unroll
    for (int off = 1; off < 16; off <<= 1){
        s1 += __shfl_xor(s1, off);
        s2 += __shfl_xor(s2, off);
    }
    if ((lane & 15) == 0){
        asb[(size_t)n * HHH + hh] = s1;
        adb[(size_t)n * HHH + hh] = s2;
    }
}

// ---------------- main GEMM: 64x128 tile, 4 waves x (64 rows x 32 cols) ----------------
__global__ __launch_bounds__(256) void gemm_mfma(const unsigned short* __restrict__ A,
                                                 const unsigned short* __restrict__ Bhi,
                                                 const unsigned short* __restrict__ Blo,
                                                 const unsigned short* __restrict__ WAhi,
                                                 const unsigned short* __restrict__ WAlo,
                                                 unsigned short* __restrict__ C,
                                                 float* __restrict__ asb,
                                                 float* __restrict__ adb){
    int tid  = threadIdx.x;
    int lane = tid & 63, wave = tid >> 6;
    int rowBase = blockIdx.y * 64;
    int colBase = blockIdx.x * 128 + wave * 32;
    int fr = lane & 15;      // fragment row (A) / col (B,D)
    int kg = lane >> 4;      // k-group 0..3
    bool doAlpha = (blockIdx.x == 0) && (wave == 0);

    v4f acc[4][2];
#pragma unroll
    for (int mi = 0; mi < 4; ++mi)
#pragma unroll
        for (int ni = 0; ni < 2; ++ni) acc[mi][ni] = (v4f){0.f, 0.f, 0.f, 0.f};
    v4f acca[4];
#pragma unroll
    for (int mi = 0; mi < 4; ++mi) acca[mi] = (v4f){0.f, 0.f, 0.f, 0.f};

    const unsigned short* aptr[4];
#pragma unroll
    for (int mi = 0; mi < 4; ++mi){
        int r = rowBase + mi * 16 + fr;
        if (r >= NN) r = NN - 1;                  // clamp; stores guarded below
        aptr[mi] = A + (size_t)r * CCH + kg * 8;
    }
    const unsigned short* bhp[2];
    const unsigned short* blp[2];
#pragma unroll
    for (int ni = 0; ni < 2; ++ni){
        int c = colBase + ni * 16 + fr;
        bhp[ni] = Bhi + (size_t)c * CCH + kg * 8;
        blp[ni] = Blo + (size_t)c * CCH + kg * 8;
    }
    const unsigned short* wahp = WAhi + (size_t)fr * CCH + kg * 8;
    const unsigned short* walp = WAlo + (size_t)fr * CCH + kg * 8;

    for (int kc = 0; kc < CCH; kc += 32){
        v8s a[4], bh[2], bl[2];
#pragma unroll
        for (int mi = 0; mi < 4; ++mi) a[mi] = *(const v8s*)(aptr[mi] + kc);
#pragma unroll
        for (int ni = 0; ni < 2; ++ni){
            bh[ni] = *(const v8s*)(bhp[ni] + kc);
            bl[ni] = *(const v8s*)(blp[ni] + kc);
        }
#pragma unroll
        for (int mi = 0; mi < 4; ++mi)
#pragma unroll
            for (int ni = 0; ni < 2; ++ni){
                acc[mi][ni] = __builtin_amdgcn_mfma_f32_16x16x32_bf16(a[mi], bh[ni], acc[mi][ni], 0, 0, 0);
                acc[mi][ni] = __builtin_amdgcn_mfma_f32_16x16x32_bf16(a[mi], bl[ni], acc[mi][ni], 0, 0, 0);
            }
        if (doAlpha){
            v8s wh = *(const v8s*)(wahp + kc);
            v8s wl = *(const v8s*)(walp + kc);
#pragma unroll
            for (int mi = 0; mi < 4; ++mi){
                acca[mi] = __builtin_amdgcn_mfma_f32_16x16x32_bf16(a[mi], wh, acca[mi], 0, 0, 0);
                acca[mi] = __builtin_amdgcn_mfma_f32_16x16x32_bf16(a[mi], wl, acca[mi], 0, 0, 0);
            }
        }
    }

    // D layout: col = lane&15 (=fr), row = (lane>>4)*4 + j (=kg*4+j)
#pragma unroll
    for (int mi = 0; mi < 4; ++mi)
#pragma unroll
        for (int j = 0; j < 4; ++j){
            int r = rowBase + mi * 16 + kg * 4 + j;
            if (r < NN){
#pragma unroll
                for (int ni = 0; ni < 2; ++ni)
                    C[(size_t)r * CCH + colBase + ni * 16 + fr] = f2bf(acc[mi][ni][j]);
            }
        }
    if (doAlpha){
#pragma unroll
        for (int mi = 0; mi < 4; ++mi)
#pragma unroll
            for (int j = 0; j < 4; ++j){
                int r = rowBase + mi * 16 + kg * 4 + j;
                if (r < NN){
                    float val = acca[mi][j];
                    if (fr < 4)      asb[(size_t)r * HHH + fr]       = val;
                    else if (fr < 8) adb[(size_t)r * HHH + (fr - 4)] = val;
                }
            }
    }
}

// ---------------- per-node softmax + aggregation: ONE WAVE PER NODE ----------------
// Fast path (deg<=64): no-max softmax; edge list PADDED to a multiple of 8
// (idx=self, alpha=0) so the entire gather runs through the 2-slot pipeline —
// no serial remainder loop. mode 0: bf16(gelu(acc+bias)); mode 1: fp32.
#define LOADG8(gg, U0, U1, U2, U3, A0, A1, A2, A3)                     \
    { int _b = (gg) << 3;                                              \
      int _e0 = _b + half, _e1 = _b + 2 + half;                        \
      int _e2 = _b + 4 + half, _e3 = _b + 6 + half;                    \
      int _i0 = ix_w[_e0], _i1 = ix_w[_e1];                            \
      int _i2 = ix_w[_e2], _i3 = ix_w[_e3];                            \
      A0 = al_w[_e0 * HHH + hc8];                                      \
      A1 = al_w[_e1 * HHH + hc8];                                      \
      A2 = al_w[_e2 * HHH + hc8];                                      \
      A3 = al_w[_e3 * HHH + hc8];                                      \
      U0 = *(const uint4*)(h + (size_t)_i0 * CCH + coff8);             \
      U1 = *(const uint4*)(h + (size_t)_i1 * CCH + coff8);             \
      U2 = *(const uint4*)(h + (size_t)_i2 * CCH + coff8);             \
      U3 = *(const uint4*)(h + (size_t)_i3 * CCH + coff8); }

#define CONSUME8(U0, U1, U2, U3, A0, A1, A2, A3)                       \
    { float4 _l0 = up4(make_uint2(U0.x, U0.y)), _h0 = up4(make_uint2(U0.z, U0.w)); \
      float4 _l1 = up4(make_uint2(U1.x, U1.y)), _h1 = up4(make_uint2(U1.z, U1.w)); \
      float4 _l2 = up4(make_uint2(U2.x, U2.y)), _h2 = up4(make_uint2(U2.z, U2.w)); \
      float4 _l3 = up4(make_uint2(U3.x, U3.y)), _h3 = up4(make_uint2(U3.z, U3.w)); \
      accLo.x += _l0.x * A0 + _l1.x * A1 + _l2.x * A2 + _l3.x * A3;    \
      accLo.y += _l0.y * A0 + _l1.y * A1 + _l2.y * A2 + _l3.y * A3;    \
      accLo.z += _l0.z * A0 + _l1.z * A1 + _l2.z * A2 + _l3.z * A3;    \
      accLo.w += _l0.w * A0 + _l1.w * A1 + _l2.w * A2 + _l3.w * A3;    \
      accHi.x += _h0.x * A0 + _h1.x * A1 + _h2.x * A2 + _h3.x * A3;    \
      accHi.y += _h0.y * A0 + _h1.y * A1 + _h2.y * A2 + _h3.y * A3;    \
      accHi.z += _h0.z * A0 + _h1.z * A1 + _h2.z * A2 + _h3.z * A3;    \
      accHi.w += _h0.w * A0 + _h1.w * A1 + _h2.w * A2 + _h3.w * A3; }

__global__ __launch_bounds__(256) void agg_k(const unsigned short* __restrict__ h,
                                             const float* __restrict__ asrc,
                                             const float* __restrict__ adst,
                                             const float* __restrict__ bias,
                                             const int* __restrict__ row_ptr,
                                             const int* __restrict__ csr_src,
                                             unsigned short* __restrict__ outg,
                                             float* __restrict__ outf,
                                             int mode){
    __shared__ float s_al[4][64 * HHH];
    __shared__ int   s_ix[4][64];

    int wave = threadIdx.x >> 6, lane = threadIdx.x & 63;
    int n = blockIdx.x * 4 + wave;
    int row0 = row_ptr[n];
    int deg  = row_ptr[n + 1] - row0;
    float4 ad = *(const float4*)(adst + (size_t)n * HHH);
    float* al_w = s_al[wave];
    int*   ix_w = s_ix[wave];

    if (deg <= 64){
        // ---- phase 1: lane k = edge k, no-max shuffle softmax ----
        int k = lane;
        int padDeg = (deg + 7) & ~7;
        int s = 0;
        float x0 = 0.f, x1 = 0.f, x2 = 0.f, x3 = 0.f;
        if (k < deg){
            s = csr_src[row0 + k];
            float4 as = *(const float4*)(asrc + (size_t)s * HHH);
            x0 = __expf(lrelu(as.x + ad.x)); x1 = __expf(lrelu(as.y + ad.y));
            x2 = __expf(lrelu(as.z + ad.z)); x3 = __expf(lrelu(as.w + ad.w));
        }
        float z0 = x0, z1 = x1, z2 = x2, z3 = x3;
#pragma unroll
        for (int off = 32; off; off >>= 1){
            z0 += __shfl_xor(z0, off);
            z1 += __shfl_xor(z1, off);
            z2 += __shfl_xor(z2, off);
            z3 += __shfl_xor(z3, off);
        }
        if (k < deg){
            float4 alv;
            alv.x = x0 / (z0 + 1e-16f);
            alv.y = x1 / (z1 + 1e-16f);
            alv.z = x2 / (z2 + 1e-16f);
            alv.w = x3 / (z3 + 1e-16f);
            ix_w[k] = s;
            *(float4*)&al_w[k * HHH] = alv;
        } else if (k < padDeg){
            ix_w[k] = n;                                // self row: always valid
            *(float4*)&al_w[k * HHH] = make_float4(0.f, 0.f, 0.f, 0.f);
        }
        // ---- phase 2: half-wave dwordx4 gather, fully pipelined (no remainder) ----
        int half  = lane >> 5;
        int l32   = lane & 31;
        int coff8 = l32 << 3;        // 8 channels per lane
        int hc8   = l32 >> 3;        // head of those channels
        float4 accLo = make_float4(0.f, 0.f, 0.f, 0.f);
        float4 accHi = make_float4(0.f, 0.f, 0.f, 0.f);

        int ng = padDeg >> 3;        // groups of 8 edges (exact after padding)
        uint4 uA0, uA1, uA2, uA3, uB0, uB1, uB2, uB3;
        float aA0, aA1, aA2, aA3, aB0, aB1, aB2, aB3;
        if (ng > 0) LOADG8(0, uA0, uA1, uA2, uA3, aA0, aA1, aA2, aA3);
        if (ng > 1) LOADG8(1, uB0, uB1, uB2, uB3, aB0, aB1, aB2, aB3);
        for (int g = 0; g < ng; g += 2){
            if (g + 2 < ng) {
                CONSUME8(uA0, uA1, uA2, uA3, aA0, aA1, aA2, aA3);
                LOADG8(g + 2, uA0, uA1, uA2, uA3, aA0, aA1, aA2, aA3);
            } else {
                CONSUME8(uA0, uA1, uA2, uA3, aA0, aA1, aA2, aA3);
            }
            if (g + 1 < ng){
                if (g + 3 < ng) {
                    CONSUME8(uB0, uB1, uB2, uB3, aB0, aB1, aB2, aB3);
                    LOADG8(g + 3, uB0, uB1, uB2, uB3, aB0, aB1, aB2, aB3);
                } else {
                    CONSUME8(uB0, uB1, uB2, uB3, aB0, aB1, aB2, aB3);
                }
            }
        }
        // combine halves
        accLo.x += __shfl_xor(accLo.x, 32); accLo.y += __shfl_xor(accLo.y, 32);
        accLo.z += __shfl_xor(accLo.z, 32); accLo.w += __shfl_xor(accLo.w, 32);
        accHi.x += __shfl_xor(accHi.x, 32); accHi.y += __shfl_xor(accHi.y, 32);
        accHi.z += __shfl_xor(accHi.z, 32); accHi.w += __shfl_xor(accHi.w, 32);
        if (half == 0){
            float4 b0v = *(const float4*)(bias + coff8);
            float4 b1v = *(const float4*)(bias + coff8 + 4);
            accLo.x += b0v.x; accLo.y += b0v.y; accLo.z += b0v.z; accLo.w += b0v.w;
            accHi.x += b1v.x; accHi.y += b1v.y; accHi.z += b1v.z; accHi.w += b1v.w;
            if (mode == 0){
                uint4 o;
                o.x = pack2(gelu_f(accLo.x), gelu_f(accLo.y));
                o.y = pack2(gelu_f(accLo.z), gelu_f(accLo.w));
                o.z = pack2(gelu_f(accHi.x), gelu_f(accHi.y));
                o.w = pack2(gelu_f(accHi.z), gelu_f(accHi.w));
                *(uint4*)(outg + (size_t)n * CCH + coff8) = o;
            } else {
                *(float4*)(outf + (size_t)n * CCH + coff8)     = accLo;
                *(float4*)(outf + (size_t)n * CCH + coff8 + 4) = accHi;
            }
        }
        return;
    }

    // ---- generic path: online softmax over 64-edge chunks (uint2 gather) ----
    int coff = lane << 2;
    int hc   = lane >> 4;
    float4 acc = make_float4(0.f, 0.f, 0.f, 0.f);
    float m0 = -INFINITY, m1 = -INFINITY, m2 = -INFINITY, m3 = -INFINITY;
    float z0 = 0.f, z1 = 0.f, z2 = 0.f, z3 = 0.f;
    for (int c0 = 0; c0 < deg; c0 += 64){
        int k = c0 + lane;
        float e0 = -INFINITY, e1 = -INFINITY, e2 = -INFINITY, e3 = -INFINITY;
        if (k < deg){
            int s = csr_src[row0 + k];
            float4 as = *(const float4*)(asrc + (size_t)s * HHH);
            e0 = lrelu(as.x + ad.x); e1 = lrelu(as.y + ad.y);
            e2 = lrelu(as.z + ad.z); e3 = lrelu(as.w + ad.w);
        }
        float c0m = e0, c1m = e1, c2m = e2, c3m = e3;
#pragma unroll
        for (int off = 32; off; off >>= 1){
            c0m = fmaxf(c0m, __shfl_xor(c0m, off));
            c1m = fmaxf(c1m, __shfl_xor(c1m, off));
            c2m = fmaxf(c2m, __shfl_xor(c2m, off));
            c3m = fmaxf(c3m, __shfl_xor(c3m, off));
        }
        float n0 = fmaxf(m0, c0m), n1 = fmaxf(m1, c1m);
        float n2 = fmaxf(m2, c2m), n3 = fmaxf(m3, c3m);
        float x0 = 0.f, x1 = 0.f, x2 = 0.f, x3 = 0.f;
        if (k < deg){
            x0 = __expf(e0 - n0); x1 = __expf(e1 - n1);
            x2 = __expf(e2 - n2); x3 = __expf(e3 - n3);
        }
        float s0 = x0, s1 = x1, s2 = x2, s3 = x3;
#pragma unroll
        for (int off = 32; off; off >>= 1){
            s0 += __shfl_xor(s0, off);
            s1 += __shfl_xor(s1, off);
            s2 += __shfl_xor(s2, off);
            s3 += __shfl_xor(s3, off);
        }
        z0 = z0 * ((m0 == -INFINITY) ? 0.f : __expf(m0 - n0)) + s0;
        z1 = z1 * ((m1 == -INFINITY) ? 0.f : __expf(m1 - n1)) + s1;
        z2 = z2 * ((m2 == -INFINITY) ? 0.f : __expf(m2 - n2)) + s2;
        z3 = z3 * ((m3 == -INFINITY) ? 0.f : __expf(m3 - n3)) + s3;
        m0 = n0; m1 = n1; m2 = n2; m3 = n3;
    }
    float iz0 = 1.f / (z0 + 1e-16f), iz1 = 1.f / (z1 + 1e-16f);
    float iz2 = 1.f / (z2 + 1e-16f), iz3 = 1.f / (z3 + 1e-16f);
    for (int c0 = 0; c0 < deg; c0 += 64){
        int k = c0 + lane;
        if (k < deg){
            int s = csr_src[row0 + k];
            float4 as = *(const float4*)(asrc + (size_t)s * HHH);
            float4 alv;
            alv.x = __expf(lrelu(as.x + ad.x) - m0) * iz0;
            alv.y = __expf(lrelu(as.y + ad.y) - m1) * iz1;
            alv.z = __expf(lrelu(as.z + ad.z) - m2) * iz2;
            alv.w = __expf(lrelu(as.w + ad.w) - m3) * iz3;
            ix_w[lane] = s;
            *(float4*)&al_w[lane * HHH] = alv;
        }
        int cnt = deg - c0; if (cnt > 64) cnt = 64;
        for (int j = 0; j < cnt; ++j){
            int i0 = ix_w[j];
            float a0 = al_w[j * HHH + hc];
            float4 v0 = up4(*(const uint2*)(h + (size_t)i0 * CCH + coff));
            acc.x += v0.x * a0; acc.y += v0.y * a0; acc.z += v0.z * a0; acc.w += v0.w * a0;
        }
    }
    float4 bv = *(const float4*)(bias + coff);
    acc.x += bv.x; acc.y += bv.y; acc.z += bv.z; acc.w += bv.w;
    if (mode == 0){
        uint2 o;
        o.x = pack2(gelu_f(acc.x), gelu_f(acc.y));
        o.y = pack2(gelu_f(acc.z), gelu_f(acc.w));
        *(uint2*)(outg + (size_t)n * CCH + coff) = o;
    } else {
        *(float4*)(outf + (size_t)n * CCH + coff) = acc;
    }
}

// ---------------- graph boundary pointers (batch is sorted) ----------------
__global__ void gptr_k(const int* __restrict__ batch, int* __restrict__ gptr){
    int i = blockIdx.x * 256 + threadIdx.x;
    if (i >= NN) return;
    int bi = batch[i];
    int bp = (i == 0) ? -1 : batch[i - 1];
    for (int g = bp + 1; g <= bi; ++g) gptr[g] = i;
    if (i == NN - 1){
        for (int g = bi + 1; g <= BB; ++g) gptr[g] = NN;
    }
}

// ---------------- pooling stage 1 ----------------
__global__ __launch_bounds__(256) void pool1_k(const float* __restrict__ h,
                                               const int* __restrict__ gptr,
                                               float* __restrict__ part){
    const int S1 = BB * PCHUNK * CCH;
    int b = blockIdx.x, j = blockIdx.y, c = threadIdx.x;
    int s = gptr[b], e = gptr[b + 1];
    int len = e - s;
    int per = (len + PCHUNK - 1) / PCHUNK;
    int r0 = s + j * per;
    int r1 = r0 + per; if (r1 > e) r1 = e;
    float mn = INFINITY, mx = -INFINITY, sm = 0.f;
    int n = r0;
    for (; n + 4 <= r1; n += 4){
        float v0 = h[(size_t)(n + 0) * CCH + c];
        float v1 = h[(size_t)(n + 1) * CCH + c];
        float v2 = h[(size_t)(n + 2) * CCH + c];
        float v3 = h[(size_t)(n + 3) * CCH + c];
        mn = fminf(mn, fminf(fminf(v0, v1), fminf(v2, v3)));
        mx = fmaxf(mx, fmaxf(fmaxf(v0, v1), fmaxf(v2, v3)));
        sm += (v0 + v1) + (v2 + v3);
    }
    for (; n < r1; ++n){
        float v = h[(size_t)n * CCH + c];
        mn = fminf(mn, v); mx = fmaxf(mx, v); sm += v;
    }
    size_t o = ((size_t)b * PCHUNK + j) * CCH + c;
    part[o] = mn; part[S1 + o] = mx; part[2 * (size_t)S1 + o] = sm;
}

// ---------------- pooling stage 2 ----------------
__global__ __launch_bounds__(256) void pool2_k(const float* __restrict__ part,
                                               const int* __restrict__ gptr,
                                               float* __restrict__ gbuf){
    const int S1 = BB * PCHUNK * CCH;
    int b = blockIdx.x, c = threadIdx.x;
    float mn = INFINITY, mx = -INFINITY, sm = 0.f;
#pragma unroll
    for (int j = 0; j < PCHUNK; ++j){
        size_t o = ((size_t)b * PCHUNK + j) * CCH + c;
        mn = fminf(mn, part[o]);
        mx = fmaxf(mx, part[S1 + o]);
        sm += part[2 * (size_t)S1 + o];
    }
    int cnt = gptr[b + 1] - gptr[b];
    float mean = sm / fmaxf((float)cnt, 1.0f);
    if (cnt == 0){ mn = 0.f; mx = 0.f; }
    gbuf[b * 4 * CCH + 0 * CCH + c] = mn;
    gbuf[b * 4 * CCH + 1 * CCH + c] = mx;
    gbuf[b * 4 * CCH + 2 * CCH + c] = mean;
    gbuf[b * 4 * CCH + 3 * CCH + c] = sm;
}

// ---------------- head: gelu(g) @ head_W + head_b ----------------
__global__ __launch_bounds__(128) void head_k(const float* __restrict__ gbuf,
                                              const float* __restrict__ head_W,
                                              const float* __restrict__ head_b,
                                              float* __restrict__ out){
    __shared__ float gs[4 * CCH];
    int b = blockIdx.x;
    int o = threadIdx.x;
    for (int k = o; k < 4 * CCH; k += 128) gs[k] = gelu_f(gbuf[b * 4 * CCH + k]);
    __syncthreads();
    float acc = head_b[o];
    for (int k = 0; k < 4 * CCH; ++k) acc += gs[k] * head_W[k * NOUTP + o];
    out[b * NOUTP + o] = acc;
}

extern "C" void kernel_launch(void* const* d_in, const int* in_sizes, int n_in,
                              void* d_out, int out_size, void* d_ws, size_t ws_size,
                              hipStream_t stream){
    const float* x        = (const float*)d_in[0];
    const int*   ei       = (const int*)  d_in[1];
    const int*   batch    = (const int*)  d_in[2];
    const float* W0       = (const float*)d_in[3];
    const float* a_src0   = (const float*)d_in[4];
    const float* a_dst0   = (const float*)d_in[5];
    const float* b0       = (const float*)d_in[6];
    const float* Ws       = (const float*)d_in[7];
    const float* a_srcs   = (const float*)d_in[8];
    const float* a_dsts   = (const float*)d_in[9];
    const float* bs       = (const float*)d_in[10];
    const float* head_W   = (const float*)d_in[11];
    const float* head_b   = (const float*)d_in[12];
    float* out = (float*)d_out;

    char* p = (char*)d_ws;
    float* buf0f = (float*)p;                   p += (size_t)NN * CCH * 4;   // fp32 final agg (pooling)
    unsigned short* buf0g = (unsigned short*)p; p += (size_t)NN * CCH * 2;   // bf16 gelu'd agg (gemm A)
    unsigned short* buf1  = (unsigned short*)p; p += (size_t)NN * CCH * 2;   // bf16 payload h_l
    float* asb  = (float*)p;                   p += (size_t)NN * HHH * 4;
    float* adb  = (float*)p;                   p += (size_t)NN * HHH * 4;
    int* row_ptr = (int*)p;                    p += 120016;                 // (N+1)*4 padded
    int* cnt     = (int*)p;                    p += (size_t)NN * 4;
    int* csr_src = (int*)p;                    p += (size_t)ETOT * 4;
    float* gbuf  = (float*)p;                  p += (size_t)BB * 4 * CCH * 4;
    int* gptr    = (int*)p;                    p += 208;
    unsigned short* wthi = (unsigned short*)p; p += (size_t)(NLAY - 1) * CCH * CCH * 2;
    unsigned short* wtlo = (unsigned short*)p; p += (size_t)(NLAY - 1) * CCH * CCH * 2;
    unsigned short* wahi = (unsigned short*)p; p += (size_t)(NLAY - 1) * 16 * CCH * 2;
    unsigned short* walo = (unsigned short*)p; p += (size_t)(NLAY - 1) * 16 * CCH * 2;
    float* pscr = (float*)p;                   p += (size_t)3 * BB * PCHUNK * CCH * 4;  // pool partials

    // ---- CSR build + weight prep ----
    hipMemsetAsync(cnt, 0, (size_t)NN * 4, stream);
    count_k<<<(ETOT + 255) / 256, 256, 0, stream>>>(ei, cnt);
    scan_k<<<1, 1024, 0, stream>>>(cnt, row_ptr);
    hipMemsetAsync(cnt, 0, (size_t)NN * 4, stream);
    scatter_k<<<(ETOT + 255) / 256, 256, 0, stream>>>(ei, row_ptr, cnt, csr_src);
    gptr_k<<<(NN + 255) / 256, 256, 0, stream>>>(batch, gptr);
    wconv_k<<<dim3(NLAY - 1, 64), 256, 0, stream>>>(Ws, wthi, wtlo);
    waconv_k<<<dim3(NLAY - 1, 8), 256, 0, stream>>>(Ws, a_srcs, a_dsts, wahi, walo);

    // ---- layer 0 (fused h0 + alpha, one wave per node) ----
    l0_fused<<<(NN + 3) / 4, 256, 0, stream>>>(x, W0, a_src0, a_dst0, buf1, asb, adb);
    agg_k<<<NN / 4, 256, 0, stream>>>(buf1, asb, adb, b0, row_ptr, csr_src,
                                      buf0g, buf0f, 0);

    // ---- layers 1..9 (alpha fused into gemm; A is bf16 gelu'd) ----
    dim3 ggrid(2, (NN + 63) / 64);
    for (int l = 1; l < NLAY; ++l){
        const unsigned short* whl = wthi + (size_t)(l - 1) * CCH * CCH;
        const unsigned short* wll = wtlo + (size_t)(l - 1) * CCH * CCH;
        const unsigned short* wal_h = wahi + (size_t)(l - 1) * 16 * CCH;
        const unsigned short* wal_l = walo + (size_t)(l - 1) * 16 * CCH;
        const float* bl  = bs + (size_t)(l - 1) * CCH;
        gemm_mfma<<<ggrid, 256, 0, stream>>>(buf0g, whl, wll, wal_h, wal_l, buf1, asb, adb);
        agg_k<<<NN / 4, 256, 0, stream>>>(buf1, asb, adb, bl, row_ptr, csr_src,
                                          buf0g, buf0f, (l == NLAY - 1) ? 1 : 0);
    }

    // ---- readout ----
    dim3 pgrid(BB, PCHUNK);
    pool1_k<<<pgrid, 256, 0, stream>>>(buf0f, gptr, pscr);
    pool2_k<<<BB, 256, 0, stream>>>(pscr, gptr, gbuf);
    head_k<<<BB, 128, 0, stream>>>(gbuf, head_W, head_b, out);
}

// Round 13
// 894.903 us; speedup vs baseline: 1.1062x; 1.0738x over previous
//
#include <hip/hip_runtime.h>
#include <math.h>

#define NN   30000
#define EE   480000
#define ETOT 510000   // EE + NN self loops
#define BB   48
#define HHH  4
#define DDD  64
#define CCH  256      // HHH*DDD
#define NINP 8
#define NOUTP 128
#define NLAY 10
#define SLOPE 0.2f
#define PCHUNK 32     // pool stage-1 chunks per graph

typedef short v8s  __attribute__((ext_vector_type(8)));
typedef float v4f  __attribute__((ext_vector_type(4)));

__device__ __forceinline__ float gelu_f(float x){
    return 0.5f * x * (1.0f + erff(x * 0.70710678118654752f));
}
__device__ __forceinline__ unsigned short f2bf(float f){
    unsigned u = __float_as_uint(f);
    unsigned r = u + 0x7FFF + ((u >> 16) & 1);   // RNE
    return (unsigned short)(r >> 16);
}
__device__ __forceinline__ float bf2f(unsigned short b){
    return __uint_as_float(((unsigned)b) << 16);
}
__device__ __forceinline__ float lrelu(float e){
    return (e > 0.f) ? e : SLOPE * e;
}
__device__ __forceinline__ unsigned pack2(float a, float b){
    return (unsigned)f2bf(a) | ((unsigned)f2bf(b) << 16);
}
// unpack 4 bf16 (little-endian packed in uint2) -> float4
__device__ __forceinline__ float4 up4(uint2 u){
    float4 r;
    r.x = __uint_as_float(u.x << 16);
    r.y = __uint_as_float(u.x & 0xFFFF0000u);
    r.z = __uint_as_float(u.y << 16);
    r.w = __uint_as_float(u.y & 0xFFFF0000u);
    return r;
}

// ---------------- CSR build ----------------
__global__ void count_k(const int* __restrict__ ei, int* __restrict__ cnt){
    int e = blockIdx.x * 256 + threadIdx.x;
    if (e >= ETOT) return;
    int d = (e < EE) ? ei[EE + e] : (e - EE);
    atomicAdd(&cnt[d], 1);
}

// single block, 1024 thr, 30 elems/thread in registers; 2 barriers total
__global__ __launch_bounds__(1024) void scan_k(const int* __restrict__ cnt, int* __restrict__ row_ptr){
    const int PER = 30;                 // 1024*30 = 30720 >= NN
    int t = threadIdx.x;
    int base = t * PER;
    int v[PER];
    int sum = 0;
#pragma unroll
    for (int i = 0; i < PER; ++i){
        int x = (base + i < NN) ? cnt[base + i] : 0;
        v[i] = sum;                     // exclusive prefix within thread
        sum += x;
    }
    int lane = t & 63, w = t >> 6;
    int inc = sum;
#pragma unroll
    for (int off = 1; off < 64; off <<= 1){
        int u = __shfl_up(inc, off);
        if (lane >= off) inc += u;
    }
    __shared__ int wtot[16], woff[16];
    if (lane == 63) wtot[w] = inc;
    __syncthreads();
    if (t == 0){
        int r = 0;
        for (int i = 0; i < 16; ++i){ woff[i] = r; r += wtot[i]; }
        row_ptr[NN] = r;
    }
    __syncthreads();
    int excl = woff[w] + (inc - sum);
#pragma unroll
    for (int i = 0; i < PER; ++i){
        if (base + i < NN) row_ptr[base + i] = excl + v[i];
    }
}

__global__ void scatter_k(const int* __restrict__ ei, const int* __restrict__ row_ptr,
                          int* __restrict__ cursor, int* __restrict__ csr_src){
    int e = blockIdx.x * 256 + threadIdx.x;
    if (e >= ETOT) return;
    int s, d;
    if (e < EE){ s = ei[e]; d = ei[EE + e]; } else { s = d = e - EE; }
    int pos = row_ptr[d] + atomicAdd(&cursor[d], 1);
    csr_src[pos] = s;
}

// ---------------- weight prep: 32x32 LDS tile transpose + bf16 hi/lo split ----------------
__global__ __launch_bounds__(256) void wconv_k(const float* __restrict__ Ws,
                                               unsigned short* __restrict__ WT_hi,
                                               unsigned short* __restrict__ WT_lo){
    __shared__ float tile[32][33];
    int l = blockIdx.x;
    int kt = (blockIdx.y >> 3) * 32;
    int nt = (blockIdx.y & 7) * 32;
    const float* W = Ws + (size_t)l * CCH * CCH;
    unsigned short* th = WT_hi + (size_t)l * CCH * CCH;
    unsigned short* tl = WT_lo + (size_t)l * CCH * CCH;
    int tx = threadIdx.x & 31, ty = threadIdx.x >> 5;
#pragma unroll
    for (int r = ty; r < 32; r += 8)
        tile[r][tx] = W[(size_t)(kt + r) * CCH + nt + tx];
    __syncthreads();
#pragma unroll
    for (int r = ty; r < 32; r += 8){
        float w = tile[tx][r];          // = W[kt+tx][nt+r]
        unsigned short h = f2bf(w);
        size_t o = (size_t)(nt + r) * CCH + kt + tx;
        th[o] = h;
        tl[o] = f2bf(w - bf2f(h));
    }
}

// ---------------- alpha-weight prep: grid (NLAY-1, 8) ----------------
__global__ __launch_bounds__(256) void waconv_k(const float* __restrict__ Ws,
                                                const float* __restrict__ a_srcs,
                                                const float* __restrict__ a_dsts,
                                                unsigned short* __restrict__ wa_hi,
                                                unsigned short* __restrict__ wa_lo){
    int l = blockIdx.x;
    int j = blockIdx.y;
    int k = threadIdx.x;
    const float* W = Ws + (size_t)l * CCH * CCH;
    const float* av = (j < 4) ? (a_srcs + (size_t)l * CCH + j * DDD)
                              : (a_dsts + (size_t)l * CCH + (j - 4) * DDD);
    int cb = (j & 3) * DDD;
    float s = 0.f;
    const float4* wp = (const float4*)(W + (size_t)k * CCH + cb);
    const float4* ap = (const float4*)av;
#pragma unroll
    for (int d = 0; d < DDD / 4; ++d){
        float4 wv = wp[d], avv = ap[d];
        s += wv.x * avv.x + wv.y * avv.y + wv.z * avv.z + wv.w * avv.w;
    }
    unsigned short hb = f2bf(s);
    wa_hi[((size_t)l * 16 + j) * CCH + k] = hb;
    wa_lo[((size_t)l * 16 + j) * CCH + k] = f2bf(s - bf2f(hb));
    if (j >= 4){  // zero the padding cols 8..15 (two per block)
        wa_hi[((size_t)l * 16 + j + 4) * CCH + k] = 0;
        wa_lo[((size_t)l * 16 + j + 4) * CCH + k] = 0;
        wa_hi[((size_t)l * 16 + j + 8) * CCH + k] = 0;
        wa_lo[((size_t)l * 16 + j + 8) * CCH + k] = 0;
    }
}

// ---------------- layer 0 fused: ONE WAVE PER NODE, no barriers ----------------
__global__ __launch_bounds__(256) void l0_fused(const float* __restrict__ x,
                                                const float* __restrict__ W0,
                                                const float* __restrict__ a_src,
                                                const float* __restrict__ a_dst,
                                                unsigned short* __restrict__ hout,
                                                float* __restrict__ asb,
                                                float* __restrict__ adb){
    int wave = threadIdx.x >> 6, lane = threadIdx.x & 63;
    int n = blockIdx.x * 4 + wave;
    if (n >= NN) return;
    int c0 = lane << 2;          // 4 channels [c0, c0+4)
    int hh = lane >> 4;          // head
    int dbase = (lane & 15) << 2;// channel-within-head base

    float xv[NINP];
#pragma unroll
    for (int k = 0; k < NINP; ++k) xv[k] = x[n * NINP + k];   // wave-uniform, L1 broadcast

    float4 acc = make_float4(0.f, 0.f, 0.f, 0.f);
#pragma unroll
    for (int k = 0; k < NINP; ++k){
        float4 w = *(const float4*)(W0 + k * CCH + c0);
        acc.x += xv[k] * w.x; acc.y += xv[k] * w.y;
        acc.z += xv[k] * w.z; acc.w += xv[k] * w.w;
    }
    uint2 o;
    o.x = pack2(acc.x, acc.y);
    o.y = pack2(acc.z, acc.w);
    *(uint2*)(hout + (size_t)n * CCH + c0) = o;

    float4 asv = *(const float4*)(a_src + hh * DDD + dbase);
    float4 adv = *(const float4*)(a_dst + hh * DDD + dbase);
    float s1 = acc.x * asv.x + acc.y * asv.y + acc.z * asv.z + acc.w * asv.w;
    float s2 = acc.x * adv.x + acc.y * adv.y + acc.z * adv.z + acc.w * adv.w;
#pragma unroll
    for (int off = 1; off < 16; off <<= 1){
        s1 += __shfl_xor(s1, off);
        s2 += __shfl_xor(s2, off);
    }
    if ((lane & 15) == 0){
        asb[(size_t)n * HHH + hh] = s1;
        adb[(size_t)n * HHH + hh] = s2;
    }
}

// ---------------- main GEMM: 128x128 tile (R8-proven), bf16 A, 2-MFMA split-B ----------------
__global__ __launch_bounds__(256) void gemm_mfma(const unsigned short* __restrict__ A,
                                                 const unsigned short* __restrict__ Bhi,
                                                 const unsigned short* __restrict__ Blo,
                                                 const unsigned short* __restrict__ WAhi,
                                                 const unsigned short* __restrict__ WAlo,
                                                 unsigned short* __restrict__ C,
                                                 float* __restrict__ asb,
                                                 float* __restrict__ adb){
    int tid  = threadIdx.x;
    int lane = tid & 63, wave = tid >> 6;
    int wr = wave >> 1, wc = wave & 1;
    int rowBase = blockIdx.y * 128 + wr * 64;
    int colBase = blockIdx.x * 128 + wc * 64;
    int fr = lane & 15;      // fragment row (A) / col (B,D)
    int kg = lane >> 4;      // k-group 0..3
    bool doAlpha = (blockIdx.x == 0) && (wc == 0);

    v4f acc[4][4];
#pragma unroll
    for (int mi = 0; mi < 4; ++mi)
#pragma unroll
        for (int ni = 0; ni < 4; ++ni) acc[mi][ni] = (v4f){0.f, 0.f, 0.f, 0.f};
    v4f acca[4];
#pragma unroll
    for (int mi = 0; mi < 4; ++mi) acca[mi] = (v4f){0.f, 0.f, 0.f, 0.f};

    const unsigned short* aptr[4];
#pragma unroll
    for (int mi = 0; mi < 4; ++mi){
        int r = rowBase + mi * 16 + fr;
        if (r >= NN) r = NN - 1;                  // clamp; stores guarded below
        aptr[mi] = A + (size_t)r * CCH + kg * 8;
    }
    const unsigned short* bhp[4];
    const unsigned short* blp[4];
#pragma unroll
    for (int ni = 0; ni < 4; ++ni){
        int c = colBase + ni * 16 + fr;
        bhp[ni] = Bhi + (size_t)c * CCH + kg * 8;
        blp[ni] = Blo + (size_t)c * CCH + kg * 8;
    }
    const unsigned short* wahp = WAhi + (size_t)fr * CCH + kg * 8;
    const unsigned short* walp = WAlo + (size_t)fr * CCH + kg * 8;

    for (int kc = 0; kc < CCH; kc += 32){
        v8s a[4], bh[4], bl[4];
#pragma unroll
        for (int mi = 0; mi < 4; ++mi) a[mi] = *(const v8s*)(aptr[mi] + kc);
#pragma unroll
        for (int ni = 0; ni < 4; ++ni){
            bh[ni] = *(const v8s*)(bhp[ni] + kc);
            bl[ni] = *(const v8s*)(blp[ni] + kc);
        }
#pragma unroll
        for (int mi = 0; mi < 4; ++mi)
#pragma unroll
            for (int ni = 0; ni < 4; ++ni){
                acc[mi][ni] = __builtin_amdgcn_mfma_f32_16x16x32_bf16(a[mi], bh[ni], acc[mi][ni], 0, 0, 0);
                acc[mi][ni] = __builtin_amdgcn_mfma_f32_16x16x32_bf16(a[mi], bl[ni], acc[mi][ni], 0, 0, 0);
            }
        if (doAlpha){
            v8s wh = *(const v8s*)(wahp + kc);
            v8s wl = *(const v8s*)(walp + kc);
#pragma unroll
            for (int mi = 0; mi < 4; ++mi){
                acca[mi] = __builtin_amdgcn_mfma_f32_16x16x32_bf16(a[mi], wh, acca[mi], 0, 0, 0);
                acca[mi] = __builtin_amdgcn_mfma_f32_16x16x32_bf16(a[mi], wl, acca[mi], 0, 0, 0);
            }
        }
    }

    // D layout: col = lane&15 (=fr), row = (lane>>4)*4 + j (=kg*4+j)
#pragma unroll
    for (int mi = 0; mi < 4; ++mi)
#pragma unroll
        for (int j = 0; j < 4; ++j){
            int r = rowBase + mi * 16 + kg * 4 + j;
            if (r < NN){
#pragma unroll
                for (int ni = 0; ni < 4; ++ni)
                    C[(size_t)r * CCH + colBase + ni * 16 + fr] = f2bf(acc[mi][ni][j]);
            }
        }
    if (doAlpha){
#pragma unroll
        for (int mi = 0; mi < 4; ++mi)
#pragma unroll
            for (int j = 0; j < 4; ++j){
                int r = rowBase + mi * 16 + kg * 4 + j;
                if (r < NN){
                    float val = acca[mi][j];
                    if (fr < 4)      asb[(size_t)r * HHH + fr]       = val;
                    else if (fr < 8) adb[(size_t)r * HHH + (fr - 4)] = val;
                }
            }
    }
}

// ---------------- per-node softmax + aggregation: ONE WAVE PER NODE ----------------
// Fast path (deg<=64): no-max softmax; edge list PADDED to a multiple of 8
// (idx=self, alpha=0) so the entire gather runs through the 2-slot pipeline.
// mode 0: bf16(gelu(acc+bias)); mode 1: fp32.
#define LOADG8(gg, U0, U1, U2, U3, A0, A1, A2, A3)                     \
    { int _b = (gg) << 3;                                              \
      int _e0 = _b + half, _e1 = _b + 2 + half;                        \
      int _e2 = _b + 4 + half, _e3 = _b + 6 + half;                    \
      int _i0 = ix_w[_e0], _i1 = ix_w[_e1];                            \
      int _i2 = ix_w[_e2], _i3 = ix_w[_e3];                            \
      A0 = al_w[_e0 * HHH + hc8];                                      \
      A1 = al_w[_e1 * HHH + hc8];                                      \
      A2 = al_w[_e2 * HHH + hc8];                                      \
      A3 = al_w[_e3 * HHH + hc8];                                      \
      U0 = *(const uint4*)(h + (size_t)_i0 * CCH + coff8);             \
      U1 = *(const uint4*)(h + (size_t)_i1 * CCH + coff8);             \
      U2 = *(const uint4*)(h + (size_t)_i2 * CCH + coff8);             \
      U3 = *(const uint4*)(h + (size_t)_i3 * CCH + coff8); }

#define CONSUME8(U0, U1, U2, U3, A0, A1, A2, A3)                       \
    { float4 _l0 = up4(make_uint2(U0.x, U0.y)), _h0 = up4(make_uint2(U0.z, U0.w)); \
      float4 _l1 = up4(make_uint2(U1.x, U1.y)), _h1 = up4(make_uint2(U1.z, U1.w)); \
      float4 _l2 = up4(make_uint2(U2.x, U2.y)), _h2 = up4(make_uint2(U2.z, U2.w)); \
      float4 _l3 = up4(make_uint2(U3.x, U3.y)), _h3 = up4(make_uint2(U3.z, U3.w)); \
      accLo.x += _l0.x * A0 + _l1.x * A1 + _l2.x * A2 + _l3.x * A3;    \
      accLo.y += _l0.y * A0 + _l1.y * A1 + _l2.y * A2 + _l3.y * A3;    \
      accLo.z += _l0.z * A0 + _l1.z * A1 + _l2.z * A2 + _l3.z * A3;    \
      accLo.w += _l0.w * A0 + _l1.w * A1 + _l2.w * A2 + _l3.w * A3;    \
      accHi.x += _h0.x * A0 + _h1.x * A1 + _h2.x * A2 + _h3.x * A3;    \
      accHi.y += _h0.y * A0 + _h1.y * A1 + _h2.y * A2 + _h3.y * A3;    \
      accHi.z += _h0.z * A0 + _h1.z * A1 + _h2.z * A2 + _h3.z * A3;    \
      accHi.w += _h0.w * A0 + _h1.w * A1 + _h2.w * A2 + _h3.w * A3; }

__global__ __launch_bounds__(256) void agg_k(const unsigned short* __restrict__ h,
                                             const float* __restrict__ asrc,
                                             const float* __restrict__ adst,
                                             const float* __restrict__ bias,
                                             const int* __restrict__ row_ptr,
                                             const int* __restrict__ csr_src,
                                             unsigned short* __restrict__ outg,
                                             float* __restrict__ outf,
                                             int mode){
    __shared__ float s_al[4][64 * HHH];
    __shared__ int   s_ix[4][64];

    int wave = threadIdx.x >> 6, lane = threadIdx.x & 63;
    int n = blockIdx.x * 4 + wave;
    int row0 = row_ptr[n];
    int deg  = row_ptr[n + 1] - row0;
    float4 ad = *(const float4*)(adst + (size_t)n * HHH);
    float* al_w = s_al[wave];
    int*   ix_w = s_ix[wave];

    if (deg <= 64){
        // ---- phase 1: lane k = edge k, no-max shuffle softmax ----
        int k = lane;
        int padDeg = (deg + 7) & ~7;
        int s = 0;
        float x0 = 0.f, x1 = 0.f, x2 = 0.f, x3 = 0.f;
        if (k < deg){
            s = csr_src[row0 + k];
            float4 as = *(const float4*)(asrc + (size_t)s * HHH);
            x0 = __expf(lrelu(as.x + ad.x)); x1 = __expf(lrelu(as.y + ad.y));
            x2 = __expf(lrelu(as.z + ad.z)); x3 = __expf(lrelu(as.w + ad.w));
        }
        float z0 = x0, z1 = x1, z2 = x2, z3 = x3;
#pragma unroll
        for (int off = 32; off; off >>= 1){
            z0 += __shfl_xor(z0, off);
            z1 += __shfl_xor(z1, off);
            z2 += __shfl_xor(z2, off);
            z3 += __shfl_xor(z3, off);
        }
        if (k < deg){
            float4 alv;
            alv.x = x0 / (z0 + 1e-16f);
            alv.y = x1 / (z1 + 1e-16f);
            alv.z = x2 / (z2 + 1e-16f);
            alv.w = x3 / (z3 + 1e-16f);
            ix_w[k] = s;
            *(float4*)&al_w[k * HHH] = alv;
        } else if (k < padDeg){
            ix_w[k] = n;                                // self row: always valid
            *(float4*)&al_w[k * HHH] = make_float4(0.f, 0.f, 0.f, 0.f);
        }
        // ---- phase 2: half-wave dwordx4 gather, fully pipelined (no remainder) ----
        int half  = lane >> 5;
        int l32   = lane & 31;
        int coff8 = l32 << 3;        // 8 channels per lane
        int hc8   = l32 >> 3;        // head of those channels
        float4 accLo = make_float4(0.f, 0.f, 0.f, 0.f);
        float4 accHi = make_float4(0.f, 0.f, 0.f, 0.f);

        int ng = padDeg >> 3;        // groups of 8 edges (exact after padding)
        uint4 uA0, uA1, uA2, uA3, uB0, uB1, uB2, uB3;
        float aA0, aA1, aA2, aA3, aB0, aB1, aB2, aB3;
        if (ng > 0) LOADG8(0, uA0, uA1, uA2, uA3, aA0, aA1, aA2, aA3);
        if (ng > 1) LOADG8(1, uB0, uB1, uB2, uB3, aB0, aB1, aB2, aB3);
        for (int g = 0; g < ng; g += 2){
            if (g + 2 < ng) {
                CONSUME8(uA0, uA1, uA2, uA3, aA0, aA1, aA2, aA3);
                LOADG8(g + 2, uA0, uA1, uA2, uA3, aA0, aA1, aA2, aA3);
            } else {
                CONSUME8(uA0, uA1, uA2, uA3, aA0, aA1, aA2, aA3);
            }
            if (g + 1 < ng){
                if (g + 3 < ng) {
                    CONSUME8(uB0, uB1, uB2, uB3, aB0, aB1, aB2, aB3);
                    LOADG8(g + 3, uB0, uB1, uB2, uB3, aB0, aB1, aB2, aB3);
                } else {
                    CONSUME8(uB0, uB1, uB2, uB3, aB0, aB1, aB2, aB3);
                }
            }
        }
        // combine halves
        accLo.x += __shfl_xor(accLo.x, 32); accLo.y += __shfl_xor(accLo.y, 32);
        accLo.z += __shfl_xor(accLo.z, 32); accLo.w += __shfl_xor(accLo.w, 32);
        accHi.x += __shfl_xor(accHi.x, 32); accHi.y += __shfl_xor(accHi.y, 32);
        accHi.z += __shfl_xor(accHi.z, 32); accHi.w += __shfl_xor(accHi.w, 32);
        if (half == 0){
            float4 b0v = *(const float4*)(bias + coff8);
            float4 b1v = *(const float4*)(bias + coff8 + 4);
            accLo.x += b0v.x; accLo.y += b0v.y; accLo.z += b0v.z; accLo.w += b0v.w;
            accHi.x += b1v.x; accHi.y += b1v.y; accHi.z += b1v.z; accHi.w += b1v.w;
            if (mode == 0){
                uint4 o;
                o.x = pack2(gelu_f(accLo.x), gelu_f(accLo.y));
                o.y = pack2(gelu_f(accLo.z), gelu_f(accLo.w));
                o.z = pack2(gelu_f(accHi.x), gelu_f(accHi.y));
                o.w = pack2(gelu_f(accHi.z), gelu_f(accHi.w));
                *(uint4*)(outg + (size_t)n * CCH + coff8) = o;
            } else {
                *(float4*)(outf + (size_t)n * CCH + coff8)     = accLo;
                *(float4*)(outf + (size_t)n * CCH + coff8 + 4) = accHi;
            }
        }
        return;
    }

    // ---- generic path: online softmax over 64-edge chunks (uint2 gather) ----
    int coff = lane << 2;
    int hc   = lane >> 4;
    float4 acc = make_float4(0.f, 0.f, 0.f, 0.f);
    float m0 = -INFINITY, m1 = -INFINITY, m2 = -INFINITY, m3 = -INFINITY;
    float z0 = 0.f, z1 = 0.f, z2 = 0.f, z3 = 0.f;
    for (int c0 = 0; c0 < deg; c0 += 64){
        int k = c0 + lane;
        float e0 = -INFINITY, e1 = -INFINITY, e2 = -INFINITY, e3 = -INFINITY;
        if (k < deg){
            int s = csr_src[row0 + k];
            float4 as = *(const float4*)(asrc + (size_t)s * HHH);
            e0 = lrelu(as.x + ad.x); e1 = lrelu(as.y + ad.y);
            e2 = lrelu(as.z + ad.z); e3 = lrelu(as.w + ad.w);
        }
        float c0m = e0, c1m = e1, c2m = e2, c3m = e3;
#pragma unroll
        for (int off = 32; off; off >>= 1){
            c0m = fmaxf(c0m, __shfl_xor(c0m, off));
            c1m = fmaxf(c1m, __shfl_xor(c1m, off));
            c2m = fmaxf(c2m, __shfl_xor(c2m, off));
            c3m = fmaxf(c3m, __shfl_xor(c3m, off));
        }
        float n0 = fmaxf(m0, c0m), n1 = fmaxf(m1, c1m);
        float n2 = fmaxf(m2, c2m), n3 = fmaxf(m3, c3m);
        float x0 = 0.f, x1 = 0.f, x2 = 0.f, x3 = 0.f;
        if (k < deg){
            x0 = __expf(e0 - n0); x1 = __expf(e1 - n1);
            x2 = __expf(e2 - n2); x3 = __expf(e3 - n3);
        }
        float s0 = x0, s1 = x1, s2 = x2, s3 = x3;
#pragma unroll
        for (int off = 32; off; off >>= 1){
            s0 += __shfl_xor(s0, off);
            s1 += __shfl_xor(s1, off);
            s2 += __shfl_xor(s2, off);
            s3 += __shfl_xor(s3, off);
        }
        z0 = z0 * ((m0 == -INFINITY) ? 0.f : __expf(m0 - n0)) + s0;
        z1 = z1 * ((m1 == -INFINITY) ? 0.f : __expf(m1 - n1)) + s1;
        z2 = z2 * ((m2 == -INFINITY) ? 0.f : __expf(m2 - n2)) + s2;
        z3 = z3 * ((m3 == -INFINITY) ? 0.f : __expf(m3 - n3)) + s3;
        m0 = n0; m1 = n1; m2 = n2; m3 = n3;
    }
    float iz0 = 1.f / (z0 + 1e-16f), iz1 = 1.f / (z1 + 1e-16f);
    float iz2 = 1.f / (z2 + 1e-16f), iz3 = 1.f / (z3 + 1e-16f);
    for (int c0 = 0; c0 < deg; c0 += 64){
        int k = c0 + lane;
        if (k < deg){
            int s = csr_src[row0 + k];
            float4 as = *(const float4*)(asrc + (size_t)s * HHH);
            float4 alv;
            alv.x = __expf(lrelu(as.x + ad.x) - m0) * iz0;
            alv.y = __expf(lrelu(as.y + ad.y) - m1) * iz1;
            alv.z = __expf(lrelu(as.z + ad.z) - m2) * iz2;
            alv.w = __expf(lrelu(as.w + ad.w) - m3) * iz3;
            ix_w[lane] = s;
            *(float4*)&al_w[lane * HHH] = alv;
        }
        int cnt = deg - c0; if (cnt > 64) cnt = 64;
        for (int j = 0; j < cnt; ++j){
            int i0 = ix_w[j];
            float a0 = al_w[j * HHH + hc];
            float4 v0 = up4(*(const uint2*)(h + (size_t)i0 * CCH + coff));
            acc.x += v0.x * a0; acc.y += v0.y * a0; acc.z += v0.z * a0; acc.w += v0.w * a0;
        }
    }
    float4 bv = *(const float4*)(bias + coff);
    acc.x += bv.x; acc.y += bv.y; acc.z += bv.z; acc.w += bv.w;
    if (mode == 0){
        uint2 o;
        o.x = pack2(gelu_f(acc.x), gelu_f(acc.y));
        o.y = pack2(gelu_f(acc.z), gelu_f(acc.w));
        *(uint2*)(outg + (size_t)n * CCH + coff) = o;
    } else {
        *(float4*)(outf + (size_t)n * CCH + coff) = acc;
    }
}

// ---------------- graph boundary pointers (batch is sorted) ----------------
__global__ void gptr_k(const int* __restrict__ batch, int* __restrict__ gptr){
    int i = blockIdx.x * 256 + threadIdx.x;
    if (i >= NN) return;
    int bi = batch[i];
    int bp = (i == 0) ? -1 : batch[i - 1];
    for (int g = bp + 1; g <= bi; ++g) gptr[g] = i;
    if (i == NN - 1){
        for (int g = bi + 1; g <= BB; ++g) gptr[g] = NN;
    }
}

// ---------------- pooling stage 1 ----------------
__global__ __launch_bounds__(256) void pool1_k(const float* __restrict__ h,
                                               const int* __restrict__ gptr,
                                               float* __restrict__ part){
    const int S1 = BB * PCHUNK * CCH;
    int b = blockIdx.x, j = blockIdx.y, c = threadIdx.x;
    int s = gptr[b], e = gptr[b + 1];
    int len = e - s;
    int per = (len + PCHUNK - 1) / PCHUNK;
    int r0 = s + j * per;
    int r1 = r0 + per; if (r1 > e) r1 = e;
    float mn = INFINITY, mx = -INFINITY, sm = 0.f;
    int n = r0;
    for (; n + 4 <= r1; n += 4){
        float v0 = h[(size_t)(n + 0) * CCH + c];
        float v1 = h[(size_t)(n + 1) * CCH + c];
        float v2 = h[(size_t)(n + 2) * CCH + c];
        float v3 = h[(size_t)(n + 3) * CCH + c];
        mn = fminf(mn, fminf(fminf(v0, v1), fminf(v2, v3)));
        mx = fmaxf(mx, fmaxf(fmaxf(v0, v1), fmaxf(v2, v3)));
        sm += (v0 + v1) + (v2 + v3);
    }
    for (; n < r1; ++n){
        float v = h[(size_t)n * CCH + c];
        mn = fminf(mn, v); mx = fmaxf(mx, v); sm += v;
    }
    size_t o = ((size_t)b * PCHUNK + j) * CCH + c;
    part[o] = mn; part[S1 + o] = mx; part[2 * (size_t)S1 + o] = sm;
}

// ---------------- pooling stage 2 ----------------
__global__ __launch_bounds__(256) void pool2_k(const float* __restrict__ part,
                                               const int* __restrict__ gptr,
                                               float* __restrict__ gbuf){
    const int S1 = BB * PCHUNK * CCH;
    int b = blockIdx.x, c = threadIdx.x;
    float mn = INFINITY, mx = -INFINITY, sm = 0.f;
#pragma unroll
    for (int j = 0; j < PCHUNK; ++j){
        size_t o = ((size_t)b * PCHUNK + j) * CCH + c;
        mn = fminf(mn, part[o]);
        mx = fmaxf(mx, part[S1 + o]);
        sm += part[2 * (size_t)S1 + o];
    }
    int cnt = gptr[b + 1] - gptr[b];
    float mean = sm / fmaxf((float)cnt, 1.0f);
    if (cnt == 0){ mn = 0.f; mx = 0.f; }
    gbuf[b * 4 * CCH + 0 * CCH + c] = mn;
    gbuf[b * 4 * CCH + 1 * CCH + c] = mx;
    gbuf[b * 4 * CCH + 2 * CCH + c] = mean;
    gbuf[b * 4 * CCH + 3 * CCH + c] = sm;
}

// ---------------- head: gelu(g) @ head_W + head_b ----------------
__global__ __launch_bounds__(128) void head_k(const float* __restrict__ gbuf,
                                              const float* __restrict__ head_W,
                                              const float* __restrict__ head_b,
                                              float* __restrict__ out){
    __shared__ float gs[4 * CCH];
    int b = blockIdx.x;
    int o = threadIdx.x;
    for (int k = o; k < 4 * CCH; k += 128) gs[k] = gelu_f(gbuf[b * 4 * CCH + k]);
    __syncthreads();
    float acc = head_b[o];
    for (int k = 0; k < 4 * CCH; ++k) acc += gs[k] * head_W[k * NOUTP + o];
    out[b * NOUTP + o] = acc;
}

extern "C" void kernel_launch(void* const* d_in, const int* in_sizes, int n_in,
                              void* d_out, int out_size, void* d_ws, size_t ws_size,
                              hipStream_t stream){
    const float* x        = (const float*)d_in[0];
    const int*   ei       = (const int*)  d_in[1];
    const int*   batch    = (const int*)  d_in[2];
    const float* W0       = (const float*)d_in[3];
    const float* a_src0   = (const float*)d_in[4];
    const float* a_dst0   = (const float*)d_in[5];
    const float* b0       = (const float*)d_in[6];
    const float* Ws       = (const float*)d_in[7];
    const float* a_srcs   = (const float*)d_in[8];
    const float* a_dsts   = (const float*)d_in[9];
    const float* bs       = (const float*)d_in[10];
    const float* head_W   = (const float*)d_in[11];
    const float* head_b   = (const float*)d_in[12];
    float* out = (float*)d_out;

    char* p = (char*)d_ws;
    float* buf0f = (float*)p;                   p += (size_t)NN * CCH * 4;   // fp32 final agg (pooling)
    unsigned short* buf0g = (unsigned short*)p; p += (size_t)NN * CCH * 2;   // bf16 gelu'd agg (gemm A)
    unsigned short* buf1  = (unsigned short*)p; p += (size_t)NN * CCH * 2;   // bf16 payload h_l
    float* asb  = (float*)p;                   p += (size_t)NN * HHH * 4;
    float* adb  = (float*)p;                   p += (size_t)NN * HHH * 4;
    int* row_ptr = (int*)p;                    p += 120016;                 // (N+1)*4 padded
    int* cnt     = (int*)p;                    p += (size_t)NN * 4;
    int* csr_src = (int*)p;                    p += (size_t)ETOT * 4;
    float* gbuf  = (float*)p;                  p += (size_t)BB * 4 * CCH * 4;
    int* gptr    = (int*)p;                    p += 208;
    unsigned short* wthi = (unsigned short*)p; p += (size_t)(NLAY - 1) * CCH * CCH * 2;
    unsigned short* wtlo = (unsigned short*)p; p += (size_t)(NLAY - 1) * CCH * CCH * 2;
    unsigned short* wahi = (unsigned short*)p; p += (size_t)(NLAY - 1) * 16 * CCH * 2;
    unsigned short* walo = (unsigned short*)p; p += (size_t)(NLAY - 1) * 16 * CCH * 2;
    float* pscr = (float*)p;                   p += (size_t)3 * BB * PCHUNK * CCH * 4;  // pool partials

    // ---- CSR build + weight prep ----
    hipMemsetAsync(cnt, 0, (size_t)NN * 4, stream);
    count_k<<<(ETOT + 255) / 256, 256, 0, stream>>>(ei, cnt);
    scan_k<<<1, 1024, 0, stream>>>(cnt, row_ptr);
    hipMemsetAsync(cnt, 0, (size_t)NN * 4, stream);
    scatter_k<<<(ETOT + 255) / 256, 256, 0, stream>>>(ei, row_ptr, cnt, csr_src);
    gptr_k<<<(NN + 255) / 256, 256, 0, stream>>>(batch, gptr);
    wconv_k<<<dim3(NLAY - 1, 64), 256, 0, stream>>>(Ws, wthi, wtlo);
    waconv_k<<<dim3(NLAY - 1, 8), 256, 0, stream>>>(Ws, a_srcs, a_dsts, wahi, walo);

    // ---- layer 0 (fused h0 + alpha, one wave per node) ----
    l0_fused<<<(NN + 3) / 4, 256, 0, stream>>>(x, W0, a_src0, a_dst0, buf1, asb, adb);
    agg_k<<<NN / 4, 256, 0, stream>>>(buf1, asb, adb, b0, row_ptr, csr_src,
                                      buf0g, buf0f, 0);

    // ---- layers 1..9 (alpha fused into gemm; A is bf16 gelu'd) ----
    dim3 ggrid(2, (NN + 127) / 128);
    for (int l = 1; l < NLAY; ++l){
        const unsigned short* whl = wthi + (size_t)(l - 1) * CCH * CCH;
        const unsigned short* wll = wtlo + (size_t)(l - 1) * CCH * CCH;
        const unsigned short* wal_h = wahi + (size_t)(l - 1) * 16 * CCH;
        const unsigned short* wal_l = walo + (size_t)(l - 1) * 16 * CCH;
        const float* bl  = bs + (size_t)(l - 1) * CCH;
        gemm_mfma<<<ggrid, 256, 0, stream>>>(buf0g, whl, wll, wal_h, wal_l, buf1, asb, adb);
        agg_k<<<NN / 4, 256, 0, stream>>>(buf1, asb, adb, bl, row_ptr, csr_src,
                                          buf0g, buf0f, (l == NLAY - 1) ? 1 : 0);
    }

    // ---- readout ----
    dim3 pgrid(BB, PCHUNK);
    pool1_k<<<pgrid, 256, 0, stream>>>(buf0f, gptr, pscr);
    pool2_k<<<BB, 256, 0, stream>>>(pscr, gptr, gbuf);
    head_k<<<BB, 128, 0, stream>>>(gbuf, head_W, head_b, out);
}